// Round 1
// baseline (6892.830 us; speedup 1.0000x reference)
//
#include <hip/hip_runtime.h>
#include <hip/hip_bf16.h>

#define N_NODES 100000
#define N_EDGES 250000
#define N_REL 4
#define N_HEAD 4
#define D_HEAD 32
#define F_IN 256
#define F_HID 128
#define F_OUT 64
#define LRELU_SLOPE 0.2f

__device__ __forceinline__ void atomic_max_f32(float* addr, float val) {
    if (val >= 0.0f) atomicMax((int*)addr, __float_as_int(val));
    else             atomicMin((unsigned int*)addr, __float_as_uint(val));
}

// C[N,128] = A[N,FIN] @ B[FIN,128], row-major
template<int FIN>
__global__ __launch_bounds__(256) void gemm_k(const float* __restrict__ A,
                                              const float* __restrict__ B,
                                              float* __restrict__ C) {
    __shared__ float As[64][36];
    __shared__ float Bs[32][132];
    const int tid = threadIdx.x;
    const int row0 = blockIdx.x * 64;
    const int ty = tid >> 4, tx = tid & 15;
    float acc[4][8];
#pragma unroll
    for (int i = 0; i < 4; ++i)
#pragma unroll
        for (int j = 0; j < 8; ++j) acc[i][j] = 0.f;

    for (int k0 = 0; k0 < FIN; k0 += 32) {
        // stage A tile 64x32 (512 float4)
#pragma unroll
        for (int l = 0; l < 2; ++l) {
            int flat = tid + l * 256;
            int r = flat >> 3, c4 = flat & 7;
            float4 v = make_float4(0.f, 0.f, 0.f, 0.f);
            if (row0 + r < N_NODES)
                v = *(const float4*)(A + (size_t)(row0 + r) * FIN + k0 + c4 * 4);
            *(float4*)(&As[r][c4 * 4]) = v;
        }
        // stage B tile 32x128 (1024 float4)
#pragma unroll
        for (int l = 0; l < 4; ++l) {
            int flat = tid + l * 256;
            int r = flat >> 5, c4 = flat & 31;
            float4 v = *(const float4*)(B + (size_t)(k0 + r) * F_HID + c4 * 4);
            *(float4*)(&Bs[r][c4 * 4]) = v;
        }
        __syncthreads();
#pragma unroll
        for (int k = 0; k < 32; ++k) {
            float a[4], b[8];
#pragma unroll
            for (int i = 0; i < 4; ++i) a[i] = As[ty + i * 16][k];
#pragma unroll
            for (int j = 0; j < 8; ++j) b[j] = Bs[k][tx + j * 16];
#pragma unroll
            for (int i = 0; i < 4; ++i)
#pragma unroll
                for (int j = 0; j < 8; ++j) acc[i][j] += a[i] * b[j];
        }
        __syncthreads();
    }
#pragma unroll
    for (int i = 0; i < 4; ++i) {
        int r = row0 + ty + i * 16;
        if (r < N_NODES) {
#pragma unroll
            for (int j = 0; j < 8; ++j)
                C[(size_t)r * F_HID + tx + j * 16] = acc[i][j];
        }
    }
}

// per (node, head): el = <feat, al>, er = <feat, ar>; init emax=-inf, denom=0
__global__ __launch_bounds__(256) void eler_k(const float* __restrict__ feat,
                                              const float* __restrict__ al,
                                              const float* __restrict__ ar,
                                              float* __restrict__ el, float* __restrict__ er,
                                              float* __restrict__ emax, float* __restrict__ denom) {
    int i = blockIdx.x * 256 + threadIdx.x;      // n*4 + h
    if (i >= N_NODES * N_HEAD) return;
    int h = i & 3;
    const float4* f4 = (const float4*)(feat + (size_t)i * D_HEAD);
    const float4* a4 = (const float4*)(al + h * D_HEAD);
    const float4* r4 = (const float4*)(ar + h * D_HEAD);
    float sl = 0.f, sr = 0.f;
#pragma unroll
    for (int q = 0; q < 8; ++q) {
        float4 f = f4[q], a = a4[q], r = r4[q];
        sl += f.x * a.x + f.y * a.y + f.z * a.z + f.w * a.w;
        sr += f.x * r.x + f.y * r.y + f.z * r.z + f.w * r.w;
    }
    el[i] = sl; er[i] = sr;
    emax[i] = -INFINITY;
    denom[i] = 0.f;
}

__global__ __launch_bounds__(256) void edge_max_k(const int* __restrict__ src,
                                                  const int* __restrict__ dst,
                                                  const float* __restrict__ el,
                                                  const float* __restrict__ er,
                                                  float* __restrict__ emax) {
    int i = blockIdx.x * 256 + threadIdx.x;      // e*4 + h
    if (i >= N_EDGES * N_HEAD) return;
    int e = i >> 2, h = i & 3;
    int s = src[e], d = dst[e];
    float v = el[s * 4 + h] + er[d * 4 + h];
    v = v > 0.f ? v : LRELU_SLOPE * v;
    atomic_max_f32(&emax[d * 4 + h], v);
}

__global__ __launch_bounds__(256) void edge_exp_k(const int* __restrict__ src,
                                                  const int* __restrict__ dst,
                                                  const float* __restrict__ el,
                                                  const float* __restrict__ er,
                                                  const float* __restrict__ emax,
                                                  float* __restrict__ denom,
                                                  float* __restrict__ abuf) {
    int i = blockIdx.x * 256 + threadIdx.x;      // e*4 + h
    if (i >= N_EDGES * N_HEAD) return;
    int e = i >> 2, h = i & 3;
    int s = src[e], d = dst[e];
    float v = el[s * 4 + h] + er[d * 4 + h];
    v = v > 0.f ? v : LRELU_SLOPE * v;
    float ee = __expf(v - emax[d * 4 + h]);
    abuf[i] = ee;
    atomicAdd(&denom[d * 4 + h], ee);
}

__global__ __launch_bounds__(256) void edge_scatter_k(const int* __restrict__ src,
                                                      const int* __restrict__ dst,
                                                      const float* __restrict__ feat,
                                                      const float* __restrict__ abuf,
                                                      const float* __restrict__ denom,
                                                      float* __restrict__ hnext) {
    int i = blockIdx.x * 256 + threadIdx.x;      // e*32 + h*8 + q   (q = float4 idx)
    if (i >= N_EDGES * 32) return;
    int e = i >> 5, sub = i & 31;
    int h = sub >> 3, q = sub & 7;
    int s = src[e], d = dst[e];
    float alpha = abuf[e * 4 + h] / fmaxf(denom[d * 4 + h], 1e-9f);
    float4 f = *(const float4*)(feat + (size_t)s * F_HID + h * D_HEAD + q * 4);
    float* o = hnext + (size_t)d * F_HID + h * D_HEAD + q * 4;
    atomicAdd(o + 0, f.x * alpha);
    atomicAdd(o + 1, f.y * alpha);
    atomicAdd(o + 2, f.z * alpha);
    atomicAdd(o + 3, f.w * alpha);
}

// hout = act(hnext + sum_r b[r]); b is [R,128] flat
__global__ __launch_bounds__(256) void bias_act_k(const float* __restrict__ hnext,
                                                  const float* __restrict__ b,
                                                  float* __restrict__ hout, int relu) {
    int i = blockIdx.x * 256 + threadIdx.x;      // n*128 + c
    if (i >= N_NODES * F_HID) return;
    int c = i & 127;
    float bs = b[c] + b[128 + c] + b[256 + c] + b[384 + c];
    float v = hnext[i] + bs;
    if (relu) v = fmaxf(v, 0.f);
    hout[i] = v;
}

// out[N,64] = H[N,128] @ W[128,64] + b
__global__ __launch_bounds__(256) void fc_k(const float* __restrict__ Hm,
                                            const float* __restrict__ Wm,
                                            const float* __restrict__ bv,
                                            float* __restrict__ out) {
    __shared__ float Ws[F_HID][F_OUT];
    __shared__ float Hs[32][F_HID];
    const int tid = threadIdx.x;
    const int n0 = blockIdx.x * 32;
    const int tx = tid & 63, ty = tid >> 6;
#pragma unroll
    for (int l = 0; l < 8; ++l) {
        int flat = tid + l * 256;
        int r = flat >> 4, c4 = flat & 15;
        *(float4*)(&Ws[r][c4 * 4]) = *(const float4*)(Wm + r * F_OUT + c4 * 4);
    }
#pragma unroll
    for (int l = 0; l < 4; ++l) {
        int flat = tid + l * 256;
        int r = flat >> 5, c4 = flat & 31;
        float4 v = make_float4(0.f, 0.f, 0.f, 0.f);
        if (n0 + r < N_NODES)
            v = *(const float4*)(Hm + (size_t)(n0 + r) * F_HID + c4 * 4);
        *(float4*)(&Hs[r][c4 * 4]) = v;
    }
    __syncthreads();
    float acc[8];
#pragma unroll
    for (int i = 0; i < 8; ++i) acc[i] = 0.f;
    for (int k = 0; k < F_HID; ++k) {
        float w = Ws[k][tx];
#pragma unroll
        for (int i = 0; i < 8; ++i) acc[i] += Hs[ty * 8 + i][k] * w;
    }
    float bb = bv[tx];
#pragma unroll
    for (int i = 0; i < 8; ++i) {
        int r = n0 + ty * 8 + i;
        if (r < N_NODES) out[(size_t)r * F_OUT + tx] = acc[i] + bb;
    }
}

extern "C" void kernel_launch(void* const* d_in, const int* in_sizes, int n_in,
                              void* d_out, int out_size, void* d_ws, size_t ws_size,
                              hipStream_t stream) {
    const float* x   = (const float*)d_in[0];
    const int*   src = (const int*)d_in[1];
    const int*   dst = (const int*)d_in[2];
    const float* W[3]  = {(const float*)d_in[3], (const float*)d_in[7],  (const float*)d_in[11]};
    const float* al[3] = {(const float*)d_in[4], (const float*)d_in[8],  (const float*)d_in[12]};
    const float* ar[3] = {(const float*)d_in[5], (const float*)d_in[9],  (const float*)d_in[13]};
    const float* bb[3] = {(const float*)d_in[6], (const float*)d_in[10], (const float*)d_in[14]};
    const float* fcW = (const float*)d_in[15];
    const float* fcb = (const float*)d_in[16];
    float* out = (float*)d_out;

    float* ws    = (float*)d_ws;
    float* hcur  = ws;                               // N*128
    float* hnext = hcur  + (size_t)N_NODES * F_HID;  // N*128
    float* feat  = hnext + (size_t)N_NODES * F_HID;  // N*128 (per relation)
    float* el    = feat  + (size_t)N_NODES * F_HID;  // N*4
    float* er    = el    + (size_t)N_NODES * N_HEAD;
    float* emax  = er    + (size_t)N_NODES * N_HEAD;
    float* denom = emax  + (size_t)N_NODES * N_HEAD;
    float* abuf  = denom + (size_t)N_NODES * N_HEAD; // E*4

    const int gemm_blocks = (N_NODES + 63) / 64;                 // 1563
    const int eler_blocks = (N_NODES * N_HEAD + 255) / 256;      // 1563
    const int edge_blocks = (N_EDGES * N_HEAD + 255) / 256;      // 3907
    const int scat_blocks = (N_EDGES * 32) / 256;                // 31250
    const int act_blocks  = (N_NODES * F_HID) / 256;             // 50000
    const int fc_blocks   = (N_NODES + 31) / 32;                 // 3125

    for (int layer = 0; layer < 3; ++layer) {
        const float* hin = (layer == 0) ? x : hcur;
        hipMemsetAsync(hnext, 0, (size_t)N_NODES * F_HID * sizeof(float), stream);
        for (int r = 0; r < N_REL; ++r) {
            if (layer == 0)
                gemm_k<F_IN><<<gemm_blocks, 256, 0, stream>>>(
                    hin, W[0] + (size_t)r * F_IN * F_HID, feat);
            else
                gemm_k<F_HID><<<gemm_blocks, 256, 0, stream>>>(
                    hin, W[layer] + (size_t)r * F_HID * F_HID, feat);
            eler_k<<<eler_blocks, 256, 0, stream>>>(
                feat, al[layer] + r * N_HEAD * D_HEAD, ar[layer] + r * N_HEAD * D_HEAD,
                el, er, emax, denom);
            edge_max_k<<<edge_blocks, 256, 0, stream>>>(
                src + (size_t)r * N_EDGES, dst + (size_t)r * N_EDGES, el, er, emax);
            edge_exp_k<<<edge_blocks, 256, 0, stream>>>(
                src + (size_t)r * N_EDGES, dst + (size_t)r * N_EDGES, el, er, emax, denom, abuf);
            edge_scatter_k<<<scat_blocks, 256, 0, stream>>>(
                src + (size_t)r * N_EDGES, dst + (size_t)r * N_EDGES, feat, abuf, denom, hnext);
        }
        bias_act_k<<<act_blocks, 256, 0, stream>>>(hnext, bb[layer], hcur, layer < 2 ? 1 : 0);
    }
    fc_k<<<fc_blocks, 256, 0, stream>>>(hcur, fcW, fcb, out);
}

// Round 2
// 1894.662 us; speedup vs baseline: 3.6380x; 3.6380x over previous
//
#include <hip/hip_runtime.h>
#include <hip/hip_bf16.h>

#define N_NODES 100000
#define N_EDGES 250000
#define N_REL 4
#define N_HEAD 4
#define D_HEAD 32
#define F_IN 256
#define F_HID 128
#define F_OUT 64
#define LRELU_SLOPE 0.2f

#define SCAN_B 256
#define NBLK ((N_NODES + SCAN_B - 1) / SCAN_B)   // 391

// ---------------- GEMM: C[N,128] = A[N,FIN] @ B[FIN,128] ----------------
template<int FIN>
__global__ __launch_bounds__(256) void gemm_k(const float* __restrict__ A,
                                              const float* __restrict__ B,
                                              float* __restrict__ C) {
    __shared__ float As[64][36];
    __shared__ float Bs[32][132];
    const int tid = threadIdx.x;
    const int row0 = blockIdx.x * 64;
    const int ty = tid >> 4, tx = tid & 15;
    float acc[4][8];
#pragma unroll
    for (int i = 0; i < 4; ++i)
#pragma unroll
        for (int j = 0; j < 8; ++j) acc[i][j] = 0.f;

    for (int k0 = 0; k0 < FIN; k0 += 32) {
#pragma unroll
        for (int l = 0; l < 2; ++l) {
            int flat = tid + l * 256;
            int r = flat >> 3, c4 = flat & 7;
            float4 v = make_float4(0.f, 0.f, 0.f, 0.f);
            if (row0 + r < N_NODES)
                v = *(const float4*)(A + (size_t)(row0 + r) * FIN + k0 + c4 * 4);
            *(float4*)(&As[r][c4 * 4]) = v;
        }
#pragma unroll
        for (int l = 0; l < 4; ++l) {
            int flat = tid + l * 256;
            int r = flat >> 5, c4 = flat & 31;
            float4 v = *(const float4*)(B + (size_t)(k0 + r) * F_HID + c4 * 4);
            *(float4*)(&Bs[r][c4 * 4]) = v;
        }
        __syncthreads();
#pragma unroll
        for (int k = 0; k < 32; ++k) {
            float a[4], b[8];
#pragma unroll
            for (int i = 0; i < 4; ++i) a[i] = As[ty + i * 16][k];
#pragma unroll
            for (int j = 0; j < 8; ++j) b[j] = Bs[k][tx + j * 16];
#pragma unroll
            for (int i = 0; i < 4; ++i)
#pragma unroll
                for (int j = 0; j < 8; ++j) acc[i][j] += a[i] * b[j];
        }
        __syncthreads();
    }
#pragma unroll
    for (int i = 0; i < 4; ++i) {
        int r = row0 + ty + i * 16;
        if (r < N_NODES) {
#pragma unroll
            for (int j = 0; j < 8; ++j)
                C[(size_t)r * F_HID + tx + j * 16] = acc[i][j];
        }
    }
}

// ---------------- CSR build ----------------
// grid (E/256, R): histogram of dst
__global__ __launch_bounds__(256) void count_k(const int* __restrict__ dst, int* __restrict__ cnt) {
    int e = blockIdx.x * 256 + threadIdx.x;
    if (e >= N_EDGES) return;
    int r = blockIdx.y;
    atomicAdd(&cnt[r * N_NODES + dst[(size_t)r * N_EDGES + e]], 1);
}

// grid (NBLK, R): per-block exclusive scan, block sums to bsum
__global__ __launch_bounds__(SCAN_B) void scan1_k(const int* __restrict__ cnt,
                                                  int* __restrict__ row, int* __restrict__ bsum) {
    __shared__ int sdata[SCAN_B];
    int r = blockIdx.y;
    int n = blockIdx.x * SCAN_B + threadIdx.x;
    int v = (n < N_NODES) ? cnt[r * N_NODES + n] : 0;
    sdata[threadIdx.x] = v;
    __syncthreads();
    for (int off = 1; off < SCAN_B; off <<= 1) {
        int t = (threadIdx.x >= off) ? sdata[threadIdx.x - off] : 0;
        __syncthreads();
        sdata[threadIdx.x] += t;
        __syncthreads();
    }
    if (n < N_NODES) row[r * (N_NODES + 1) + n] = sdata[threadIdx.x] - v;
    if (threadIdx.x == SCAN_B - 1) bsum[r * NBLK + blockIdx.x] = sdata[threadIdx.x];
}

// grid (R), block 512: exclusive scan of block sums
__global__ __launch_bounds__(512) void scan2_k(int* __restrict__ bsum) {
    __shared__ int sdata[512];
    int r = blockIdx.x;
    int v = (threadIdx.x < NBLK) ? bsum[r * NBLK + threadIdx.x] : 0;
    sdata[threadIdx.x] = v;
    __syncthreads();
    for (int off = 1; off < 512; off <<= 1) {
        int t = (threadIdx.x >= off) ? sdata[threadIdx.x - off] : 0;
        __syncthreads();
        sdata[threadIdx.x] += t;
        __syncthreads();
    }
    if (threadIdx.x < NBLK) bsum[r * NBLK + threadIdx.x] = sdata[threadIdx.x] - v;
}

// grid ((N+1)/256+1, R): add block offsets; set row[N]=E
__global__ __launch_bounds__(256) void scan3_k(int* __restrict__ row, const int* __restrict__ bsum) {
    int r = blockIdx.y;
    int n = blockIdx.x * 256 + threadIdx.x;
    if (n > N_NODES) return;
    if (n == N_NODES) { row[r * (N_NODES + 1) + N_NODES] = N_EDGES; return; }
    row[r * (N_NODES + 1) + n] += bsum[r * NBLK + n / SCAN_B];
}

// grid (E/256, R): scatter edge srcs into CSR buckets
__global__ __launch_bounds__(256) void fill_k(const int* __restrict__ src, const int* __restrict__ dst,
                                              const int* __restrict__ row, int* __restrict__ cursor,
                                              int* __restrict__ csr_src) {
    int e = blockIdx.x * 256 + threadIdx.x;
    if (e >= N_EDGES) return;
    int r = blockIdx.y;
    int s = src[(size_t)r * N_EDGES + e];
    int d = dst[(size_t)r * N_EDGES + e];
    int p = row[r * (N_NODES + 1) + d] + atomicAdd(&cursor[r * N_NODES + d], 1);
    csr_src[(size_t)r * N_EDGES + p] = s;
}

// ---------------- per-(layer,relation) edge phases ----------------
// el/er per (node, head)
__global__ __launch_bounds__(256) void eler_k(const float* __restrict__ feat,
                                              const float* __restrict__ al,
                                              const float* __restrict__ ar,
                                              float* __restrict__ el, float* __restrict__ er) {
    int i = blockIdx.x * 256 + threadIdx.x;      // n*4 + h
    if (i >= N_NODES * N_HEAD) return;
    int h = i & 3;
    const float4* f4 = (const float4*)(feat + (size_t)i * D_HEAD);
    const float4* a4 = (const float4*)(al + h * D_HEAD);
    const float4* r4 = (const float4*)(ar + h * D_HEAD);
    float sl = 0.f, sr = 0.f;
#pragma unroll
    for (int q = 0; q < 8; ++q) {
        float4 f = f4[q], a = a4[q], r = r4[q];
        sl += f.x * a.x + f.y * a.y + f.z * a.z + f.w * a.w;
        sr += f.x * r.x + f.y * r.y + f.z * r.z + f.w * r.w;
    }
    el[i] = sl; er[i] = sr;
}

// per (node, head): softmax max + exp-sum over CSR edges; ee into abuf, 1/denom out
__global__ __launch_bounds__(256) void alpha_k(const int* __restrict__ csr_src,
                                               const int* __restrict__ row,
                                               const float* __restrict__ el,
                                               const float* __restrict__ er,
                                               float* __restrict__ abuf,
                                               float* __restrict__ invden) {
    int i = blockIdx.x * 256 + threadIdx.x;      // n*4 + h
    if (i >= N_NODES * N_HEAD) return;
    int n = i >> 2, h = i & 3;
    int st = row[n], en = row[n + 1];
    float erd = er[i];
    float m = -INFINITY;
    for (int p = st; p < en; ++p) {
        float v = el[csr_src[p] * 4 + h] + erd;
        v = v > 0.f ? v : LRELU_SLOPE * v;
        m = fmaxf(m, v);
    }
    float sum = 0.f;
    for (int p = st; p < en; ++p) {
        float v = el[csr_src[p] * 4 + h] + erd;
        v = v > 0.f ? v : LRELU_SLOPE * v;
        float ee = __expf(v - m);
        abuf[p * 4 + h] = ee;
        sum += ee;
    }
    invden[i] = 1.f / fmaxf(sum, 1e-9f);
}

// per (node, float4 chunk): gather ee-weighted src feats, scale by 1/denom, RMW hnext
template<bool FIRST>
__global__ __launch_bounds__(256) void gather_k(const int* __restrict__ csr_src,
                                                const int* __restrict__ row,
                                                const float* __restrict__ feat,
                                                const float* __restrict__ abuf,
                                                const float* __restrict__ invden,
                                                float* __restrict__ hnext) {
    int j = blockIdx.x * 256 + threadIdx.x;      // n*32 + sub
    if (j >= N_NODES * 32) return;
    int n = j >> 5, sub = j & 31;
    int h = sub >> 3;
    int st = row[n], en = row[n + 1];
    float ax = 0.f, ay = 0.f, az = 0.f, aw = 0.f;
    for (int p = st; p < en; ++p) {
        int s = csr_src[p];
        float w = abuf[p * 4 + h];
        float4 f = *(const float4*)(feat + (size_t)s * F_HID + sub * 4);
        ax += w * f.x; ay += w * f.y; az += w * f.z; aw += w * f.w;
    }
    float id = invden[n * 4 + h];
    float* o = hnext + (size_t)n * F_HID + sub * 4;
    if (FIRST) {
        float4 res = make_float4(ax * id, ay * id, az * id, aw * id);
        *(float4*)o = res;
    } else {
        float4 cur = *(float4*)o;
        cur.x += ax * id; cur.y += ay * id; cur.z += az * id; cur.w += aw * id;
        *(float4*)o = cur;
    }
}

// hout = act(hnext + sum_r b[r])
__global__ __launch_bounds__(256) void bias_act_k(const float* __restrict__ hnext,
                                                  const float* __restrict__ b,
                                                  float* __restrict__ hout, int relu) {
    int i = blockIdx.x * 256 + threadIdx.x;
    if (i >= N_NODES * F_HID) return;
    int c = i & 127;
    float bs = b[c] + b[128 + c] + b[256 + c] + b[384 + c];
    float v = hnext[i] + bs;
    if (relu) v = fmaxf(v, 0.f);
    hout[i] = v;
}

// out[N,64] = H[N,128] @ W[128,64] + b
__global__ __launch_bounds__(256) void fc_k(const float* __restrict__ Hm,
                                            const float* __restrict__ Wm,
                                            const float* __restrict__ bv,
                                            float* __restrict__ out) {
    __shared__ float Ws[F_HID][F_OUT];
    __shared__ float Hs[32][F_HID];
    const int tid = threadIdx.x;
    const int n0 = blockIdx.x * 32;
    const int tx = tid & 63, ty = tid >> 6;
#pragma unroll
    for (int l = 0; l < 8; ++l) {
        int flat = tid + l * 256;
        int r = flat >> 4, c4 = flat & 15;
        *(float4*)(&Ws[r][c4 * 4]) = *(const float4*)(Wm + r * F_OUT + c4 * 4);
    }
#pragma unroll
    for (int l = 0; l < 4; ++l) {
        int flat = tid + l * 256;
        int r = flat >> 5, c4 = flat & 31;
        float4 v = make_float4(0.f, 0.f, 0.f, 0.f);
        if (n0 + r < N_NODES)
            v = *(const float4*)(Hm + (size_t)(n0 + r) * F_HID + c4 * 4);
        *(float4*)(&Hs[r][c4 * 4]) = v;
    }
    __syncthreads();
    float acc[8];
#pragma unroll
    for (int i = 0; i < 8; ++i) acc[i] = 0.f;
    for (int k = 0; k < F_HID; ++k) {
        float w = Ws[k][tx];
#pragma unroll
        for (int i = 0; i < 8; ++i) acc[i] += Hs[ty * 8 + i][k] * w;
    }
    float bb = bv[tx];
#pragma unroll
    for (int i = 0; i < 8; ++i) {
        int r = n0 + ty * 8 + i;
        if (r < N_NODES) out[(size_t)r * F_OUT + tx] = acc[i] + bb;
    }
}

extern "C" void kernel_launch(void* const* d_in, const int* in_sizes, int n_in,
                              void* d_out, int out_size, void* d_ws, size_t ws_size,
                              hipStream_t stream) {
    const float* x   = (const float*)d_in[0];
    const int*   src = (const int*)d_in[1];
    const int*   dst = (const int*)d_in[2];
    const float* W[3]  = {(const float*)d_in[3], (const float*)d_in[7],  (const float*)d_in[11]};
    const float* al[3] = {(const float*)d_in[4], (const float*)d_in[8],  (const float*)d_in[12]};
    const float* ar[3] = {(const float*)d_in[5], (const float*)d_in[9],  (const float*)d_in[13]};
    const float* bb[3] = {(const float*)d_in[6], (const float*)d_in[10], (const float*)d_in[14]};
    const float* fcW = (const float*)d_in[15];
    const float* fcb = (const float*)d_in[16];
    float* out = (float*)d_out;

    // ---- workspace layout (floats unless noted) ----
    float* ws    = (float*)d_ws;
    float* hcur  = ws;                                    // N*128
    float* hnext = hcur  + (size_t)N_NODES * F_HID;       // N*128
    float* feat  = hnext + (size_t)N_NODES * F_HID;       // N*128
    float* el    = feat  + (size_t)N_NODES * F_HID;       // N*4
    float* er    = el    + (size_t)N_NODES * N_HEAD;      // N*4
    float* invd  = er    + (size_t)N_NODES * N_HEAD;      // N*4
    float* abuf  = invd  + (size_t)N_NODES * N_HEAD;      // E*4
    int*   cnt     = (int*)(abuf + (size_t)N_EDGES * N_HEAD);   // R*N
    int*   cursor  = cnt    + (size_t)N_REL * N_NODES;          // R*N
    int*   rowp    = cursor + (size_t)N_REL * N_NODES;          // R*(N+1)
    int*   bsum    = rowp   + (size_t)N_REL * (N_NODES + 1);    // R*NBLK
    int*   csr_src = bsum   + (size_t)N_REL * NBLK;             // R*E

    const int eblk = (N_EDGES + 255) / 256;
    const dim3 egrid(eblk, N_REL);

    // ---- CSR build (once per call, reused across layers) ----
    hipMemsetAsync(cnt, 0, 2 * (size_t)N_REL * N_NODES * sizeof(int), stream);
    count_k<<<egrid, 256, 0, stream>>>(dst, cnt);
    scan1_k<<<dim3(NBLK, N_REL), SCAN_B, 0, stream>>>(cnt, rowp, bsum);
    scan2_k<<<N_REL, 512, 0, stream>>>(bsum);
    scan3_k<<<dim3((N_NODES + 256) / 256, N_REL), 256, 0, stream>>>(rowp, bsum);
    fill_k<<<egrid, 256, 0, stream>>>(src, dst, rowp, cursor, csr_src);

    const int gemm_blocks = (N_NODES + 63) / 64;
    const int nh_blocks   = (N_NODES * N_HEAD + 255) / 256;
    const int g_blocks    = (N_NODES * 32 + 255) / 256;
    const int act_blocks  = (N_NODES * F_HID) / 256;
    const int fc_blocks   = (N_NODES + 31) / 32;

    for (int layer = 0; layer < 3; ++layer) {
        const float* hin = (layer == 0) ? x : hcur;
        for (int r = 0; r < N_REL; ++r) {
            const int* row_r = rowp + (size_t)r * (N_NODES + 1);
            const int* csr_r = csr_src + (size_t)r * N_EDGES;
            if (layer == 0)
                gemm_k<F_IN><<<gemm_blocks, 256, 0, stream>>>(
                    hin, W[0] + (size_t)r * F_IN * F_HID, feat);
            else
                gemm_k<F_HID><<<gemm_blocks, 256, 0, stream>>>(
                    hin, W[layer] + (size_t)r * F_HID * F_HID, feat);
            eler_k<<<nh_blocks, 256, 0, stream>>>(
                feat, al[layer] + r * N_HEAD * D_HEAD, ar[layer] + r * N_HEAD * D_HEAD, el, er);
            alpha_k<<<nh_blocks, 256, 0, stream>>>(csr_r, row_r, el, er, abuf, invd);
            if (r == 0)
                gather_k<true><<<g_blocks, 256, 0, stream>>>(csr_r, row_r, feat, abuf, invd, hnext);
            else
                gather_k<false><<<g_blocks, 256, 0, stream>>>(csr_r, row_r, feat, abuf, invd, hnext);
        }
        bias_act_k<<<act_blocks, 256, 0, stream>>>(hnext, bb[layer], hcur, layer < 2 ? 1 : 0);
    }
    fc_k<<<fc_blocks, 256, 0, stream>>>(hcur, fcW, fcb, out);
}

// Round 3
// 1027.887 us; speedup vs baseline: 6.7058x; 1.8433x over previous
//
#include <hip/hip_runtime.h>
#include <hip/hip_bf16.h>

#define N_NODES 100000
#define N_EDGES 250000
#define N_REL 4
#define N_HEAD 4
#define D_HEAD 32
#define F_IN 256
#define F_HID 128
#define F_OUT 64
#define LRELU_SLOPE 0.2f

#define SCAN_B 256
#define NBLK ((N_NODES + SCAN_B - 1) / SCAN_B)   // 391

typedef __attribute__((ext_vector_type(8))) short s16x8;
typedef __attribute__((ext_vector_type(8))) unsigned short u16x8;
typedef __attribute__((ext_vector_type(4))) unsigned short u16x4;
typedef __attribute__((ext_vector_type(4))) float f32x4;

__device__ __forceinline__ float bf2f(unsigned short u) {
    return __uint_as_float(((unsigned int)u) << 16);
}
__device__ __forceinline__ unsigned short f2bf(float f) {
    unsigned int x = __float_as_uint(f);
    unsigned int r = x + 0x7fffu + ((x >> 16) & 1u);
    return (unsigned short)(r >> 16);
}
__device__ __forceinline__ void gload_lds16(const void* g, void* l) {
    __builtin_amdgcn_global_load_lds(
        (const __attribute__((address_space(1))) unsigned int*)g,
        (__attribute__((address_space(3))) unsigned int*)l, 16, 0, 0);
}

// ---------------- MFMA GEMM: Cbf[N,128] = Abf[N,FIN] @ Bt[128,FIN]^T ----------------
// Abf row-major bf16; Bt = W^T row-major bf16 (Bt[n][k] = W[k][n]); C out bf16.
template<int FIN>
__global__ __launch_bounds__(256) void gemm_mfma_k(const unsigned short* __restrict__ A,
                                                   const unsigned short* __restrict__ Bt,
                                                   unsigned short* __restrict__ C) {
    __shared__ short As[128 * 64];   // [row][k] bf16, XOR-swizzled chunks
    __shared__ short Bs[128 * 64];   // [n][k] bf16, XOR-swizzled chunks
    const int tid = threadIdx.x;
    const int lane = tid & 63;
    const int wave = tid >> 6;
    const int wr = wave >> 1, wc = wave & 1;
    const int row0 = blockIdx.x * 128;

    f32x4 acc[4][4];
#pragma unroll
    for (int m = 0; m < 4; ++m)
#pragma unroll
        for (int n = 0; n < 4; ++n) acc[m][n] = (f32x4)0.f;

    for (int k0 = 0; k0 < FIN; k0 += 64) {
        if (k0) __syncthreads();
        // stage A tile 128x64 (4 x 256 lanes x 16B); pre-swizzle global source chunk
#pragma unroll
        for (int i = 0; i < 4; ++i) {
            int flat = i * 256 + tid;
            int r = flat >> 3, ch = flat & 7;
            int sch = ch ^ (r & 7);
            int grow = row0 + r; if (grow > N_NODES - 1) grow = N_NODES - 1;
            gload_lds16(A + (size_t)grow * FIN + k0 + sch * 8, As + (size_t)flat * 8);
        }
        // stage B tile 128x64
#pragma unroll
        for (int i = 0; i < 4; ++i) {
            int flat = i * 256 + tid;
            int r = flat >> 3, ch = flat & 7;
            int sch = ch ^ (r & 7);
            gload_lds16(Bt + (size_t)r * FIN + k0 + sch * 8, Bs + (size_t)flat * 8);
        }
        __syncthreads();
#pragma unroll
        for (int kk = 0; kk < 2; ++kk) {
            s16x8 a[4], b[4];
            const int kb = kk * 64 + (lane >> 4) * 16;   // byte offset of 8-elem k-group
#pragma unroll
            for (int m = 0; m < 4; ++m) {
                int r = wr * 64 + m * 16 + (lane & 15);
                int off = r * 128 + (kb ^ ((r & 7) << 4));
                a[m] = *(const s16x8*)((const char*)As + off);
            }
#pragma unroll
            for (int n = 0; n < 4; ++n) {
                int r = wc * 64 + n * 16 + (lane & 15);
                int off = r * 128 + (kb ^ ((r & 7) << 4));
                b[n] = *(const s16x8*)((const char*)Bs + off);
            }
#pragma unroll
            for (int m = 0; m < 4; ++m)
#pragma unroll
                for (int n = 0; n < 4; ++n)
                    acc[m][n] = __builtin_amdgcn_mfma_f32_16x16x32_bf16(a[m], b[n], acc[m][n], 0, 0, 0);
        }
    }
    // epilogue: C/D layout col=lane&15, row=(lane>>4)*4+q
#pragma unroll
    for (int m = 0; m < 4; ++m) {
#pragma unroll
        for (int q = 0; q < 4; ++q) {
            int r = row0 + wr * 64 + m * 16 + (lane >> 4) * 4 + q;
            if (r < N_NODES) {
#pragma unroll
                for (int n = 0; n < 4; ++n) {
                    int c = wc * 64 + n * 16 + (lane & 15);
                    C[(size_t)r * F_HID + c] = f2bf(acc[m][n][q]);
                }
            }
        }
    }
}

// ---------------- weight prep: W[R][K][128] f32 -> Wt[R][128][K] bf16 ----------------
template<int K>
__global__ __launch_bounds__(256) void wprep_k(const float* __restrict__ W,
                                               unsigned short* __restrict__ Wt) {
    int i = blockIdx.x * 256 + threadIdx.x;     // r*K*128 + k*128 + n
    if (i >= N_REL * K * 128) return;
    int r = i / (K * 128);
    int rem = i - r * K * 128;
    int k = rem >> 7, n = rem & 127;
    Wt[(size_t)r * 128 * K + (size_t)n * K + k] = f2bf(W[i]);
}

// cast f32 -> bf16, 4 elements/thread
__global__ __launch_bounds__(256) void cast_k(const float* __restrict__ in,
                                              unsigned short* __restrict__ out, int n4) {
    int i = blockIdx.x * 256 + threadIdx.x;
    if (i >= n4) return;
    float4 v = *(const float4*)(in + (size_t)i * 4);
    u16x4 o = {f2bf(v.x), f2bf(v.y), f2bf(v.z), f2bf(v.w)};
    *(u16x4*)(out + (size_t)i * 4) = o;
}

// ---------------- CSR build ----------------
__global__ __launch_bounds__(256) void count_k(const int* __restrict__ dst, int* __restrict__ cnt) {
    int e = blockIdx.x * 256 + threadIdx.x;
    if (e >= N_EDGES) return;
    int r = blockIdx.y;
    atomicAdd(&cnt[r * N_NODES + dst[(size_t)r * N_EDGES + e]], 1);
}

__global__ __launch_bounds__(SCAN_B) void scan1_k(const int* __restrict__ cnt,
                                                  int* __restrict__ row, int* __restrict__ bsum) {
    __shared__ int sdata[SCAN_B];
    int r = blockIdx.y;
    int n = blockIdx.x * SCAN_B + threadIdx.x;
    int v = (n < N_NODES) ? cnt[r * N_NODES + n] : 0;
    sdata[threadIdx.x] = v;
    __syncthreads();
    for (int off = 1; off < SCAN_B; off <<= 1) {
        int t = (threadIdx.x >= off) ? sdata[threadIdx.x - off] : 0;
        __syncthreads();
        sdata[threadIdx.x] += t;
        __syncthreads();
    }
    if (n < N_NODES) row[r * (N_NODES + 1) + n] = sdata[threadIdx.x] - v;
    if (threadIdx.x == SCAN_B - 1) bsum[r * NBLK + blockIdx.x] = sdata[threadIdx.x];
}

__global__ __launch_bounds__(512) void scan2_k(int* __restrict__ bsum) {
    __shared__ int sdata[512];
    int r = blockIdx.x;
    int v = (threadIdx.x < NBLK) ? bsum[r * NBLK + threadIdx.x] : 0;
    sdata[threadIdx.x] = v;
    __syncthreads();
    for (int off = 1; off < 512; off <<= 1) {
        int t = (threadIdx.x >= off) ? sdata[threadIdx.x - off] : 0;
        __syncthreads();
        sdata[threadIdx.x] += t;
        __syncthreads();
    }
    if (threadIdx.x < NBLK) bsum[r * NBLK + threadIdx.x] = sdata[threadIdx.x] - v;
}

__global__ __launch_bounds__(256) void scan3_k(int* __restrict__ row, const int* __restrict__ bsum) {
    int r = blockIdx.y;
    int n = blockIdx.x * 256 + threadIdx.x;
    if (n > N_NODES) return;
    if (n == N_NODES) { row[r * (N_NODES + 1) + N_NODES] = N_EDGES; return; }
    row[r * (N_NODES + 1) + n] += bsum[r * NBLK + n / SCAN_B];
}

__global__ __launch_bounds__(256) void fill_k(const int* __restrict__ src, const int* __restrict__ dst,
                                              const int* __restrict__ row, int* __restrict__ cursor,
                                              int* __restrict__ csr_src) {
    int e = blockIdx.x * 256 + threadIdx.x;
    if (e >= N_EDGES) return;
    int r = blockIdx.y;
    int s = src[(size_t)r * N_EDGES + e];
    int d = dst[(size_t)r * N_EDGES + e];
    int p = row[r * (N_NODES + 1) + d] + atomicAdd(&cursor[r * N_NODES + d], 1);
    csr_src[(size_t)r * N_EDGES + p] = s;
}

// ---------------- edge phases ----------------
__global__ __launch_bounds__(256) void eler_k(const unsigned short* __restrict__ feat,
                                              const float* __restrict__ al,
                                              const float* __restrict__ ar,
                                              float* __restrict__ el, float* __restrict__ er) {
    int i = blockIdx.x * 256 + threadIdx.x;      // n*4 + h
    if (i >= N_NODES * N_HEAD) return;
    int h = i & 3;
    const u16x8* f8 = (const u16x8*)(feat + (size_t)i * D_HEAD);
    float sl = 0.f, sr = 0.f;
#pragma unroll
    for (int q = 0; q < 4; ++q) {
        u16x8 f = f8[q];
#pragma unroll
        for (int j = 0; j < 8; ++j) {
            float fv = bf2f(f[j]);
            sl += fv * al[h * 32 + q * 8 + j];
            sr += fv * ar[h * 32 + q * 8 + j];
        }
    }
    el[i] = sl; er[i] = sr;
}

__global__ __launch_bounds__(256) void alpha_k(const int* __restrict__ csr_src,
                                               const int* __restrict__ row,
                                               const float* __restrict__ el,
                                               const float* __restrict__ er,
                                               float* __restrict__ abuf,
                                               float* __restrict__ invden) {
    int i = blockIdx.x * 256 + threadIdx.x;      // n*4 + h
    if (i >= N_NODES * N_HEAD) return;
    int n = i >> 2, h = i & 3;
    int st = row[n], en = row[n + 1];
    float erd = er[i];
    float m = -INFINITY;
    for (int p = st; p < en; ++p) {
        float v = el[csr_src[p] * 4 + h] + erd;
        v = v > 0.f ? v : LRELU_SLOPE * v;
        m = fmaxf(m, v);
    }
    float sum = 0.f;
    for (int p = st; p < en; ++p) {
        float v = el[csr_src[p] * 4 + h] + erd;
        v = v > 0.f ? v : LRELU_SLOPE * v;
        float ee = __expf(v - m);
        abuf[p * 4 + h] = ee;
        sum += ee;
    }
    invden[i] = 1.f / fmaxf(sum, 1e-9f);
}

// per (node, 8-channel chunk): gather ee-weighted bf16 src feats
template<bool FIRST>
__global__ __launch_bounds__(256) void gather_k(const int* __restrict__ csr_src,
                                                const int* __restrict__ row,
                                                const unsigned short* __restrict__ feat,
                                                const float* __restrict__ abuf,
                                                const float* __restrict__ invden,
                                                float* __restrict__ hnext) {
    int j = blockIdx.x * 256 + threadIdx.x;      // n*16 + sub
    if (j >= N_NODES * 16) return;
    int n = j >> 4, sub = j & 15;
    int h = sub >> 2;
    int st = row[n], en = row[n + 1];
    float acc[8];
#pragma unroll
    for (int q = 0; q < 8; ++q) acc[q] = 0.f;
    for (int p = st; p < en; ++p) {
        int s = csr_src[p];
        float w = abuf[p * 4 + h];
        u16x8 f = *(const u16x8*)(feat + (size_t)s * F_HID + sub * 8);
#pragma unroll
        for (int q = 0; q < 8; ++q) acc[q] += w * bf2f(f[q]);
    }
    float id = invden[n * 4 + h];
    float* o = hnext + (size_t)n * F_HID + sub * 8;
    if (FIRST) {
        float4 r0 = make_float4(acc[0] * id, acc[1] * id, acc[2] * id, acc[3] * id);
        float4 r1 = make_float4(acc[4] * id, acc[5] * id, acc[6] * id, acc[7] * id);
        *(float4*)o = r0;
        *(float4*)(o + 4) = r1;
    } else {
        float4 c0 = *(float4*)o, c1 = *(float4*)(o + 4);
        c0.x += acc[0] * id; c0.y += acc[1] * id; c0.z += acc[2] * id; c0.w += acc[3] * id;
        c1.x += acc[4] * id; c1.y += acc[5] * id; c1.z += acc[6] * id; c1.w += acc[7] * id;
        *(float4*)o = c0;
        *(float4*)(o + 4) = c1;
    }
}

// hbf = act(hnext + sum_r b[r]) -> bf16, 4 channels/thread
__global__ __launch_bounds__(256) void bias_act_k(const float* __restrict__ hnext,
                                                  const float* __restrict__ b,
                                                  unsigned short* __restrict__ hbf, int relu) {
    int i = blockIdx.x * 256 + threadIdx.x;      // n*32 + c4
    if (i >= N_NODES * 32) return;
    int c = (i & 31) * 4;
    float4 v = *(const float4*)(hnext + (size_t)i * 4);
    float r[4] = {v.x, v.y, v.z, v.w};
    u16x4 o;
#pragma unroll
    for (int q = 0; q < 4; ++q) {
        float bs = b[c + q] + b[128 + c + q] + b[256 + c + q] + b[384 + c + q];
        float t = r[q] + bs;
        if (relu) t = fmaxf(t, 0.f);
        o[q] = f2bf(t);
    }
    *(u16x4*)(hbf + (size_t)i * 4) = o;
}

// out[N,64] = H_bf16[N,128] @ W[128,64] + b
__global__ __launch_bounds__(256) void fc_k(const unsigned short* __restrict__ Hm,
                                            const float* __restrict__ Wm,
                                            const float* __restrict__ bv,
                                            float* __restrict__ out) {
    __shared__ float Ws[F_HID][F_OUT];
    __shared__ float Hs[32][F_HID];
    const int tid = threadIdx.x;
    const int n0 = blockIdx.x * 32;
    const int tx = tid & 63, ty = tid >> 6;
#pragma unroll
    for (int l = 0; l < 8; ++l) {
        int flat = tid + l * 256;
        int r = flat >> 4, c4 = flat & 15;
        *(float4*)(&Ws[r][c4 * 4]) = *(const float4*)(Wm + r * F_OUT + c4 * 4);
    }
#pragma unroll
    for (int l = 0; l < 2; ++l) {
        int flat = tid + l * 256;
        int r = flat >> 4, c8 = flat & 15;
        u16x8 v = (u16x8)0;
        if (n0 + r < N_NODES)
            v = *(const u16x8*)(Hm + (size_t)(n0 + r) * F_HID + c8 * 8);
#pragma unroll
        for (int q = 0; q < 8; ++q) Hs[r][c8 * 8 + q] = bf2f(v[q]);
    }
    __syncthreads();
    float acc[8];
#pragma unroll
    for (int i = 0; i < 8; ++i) acc[i] = 0.f;
    for (int k = 0; k < F_HID; ++k) {
        float w = Ws[k][tx];
#pragma unroll
        for (int i = 0; i < 8; ++i) acc[i] += Hs[ty * 8 + i][k] * w;
    }
    float bb = bv[tx];
#pragma unroll
    for (int i = 0; i < 8; ++i) {
        int r = n0 + ty * 8 + i;
        if (r < N_NODES) out[(size_t)r * F_OUT + tx] = acc[i] + bb;
    }
}

extern "C" void kernel_launch(void* const* d_in, const int* in_sizes, int n_in,
                              void* d_out, int out_size, void* d_ws, size_t ws_size,
                              hipStream_t stream) {
    const float* x   = (const float*)d_in[0];
    const int*   src = (const int*)d_in[1];
    const int*   dst = (const int*)d_in[2];
    const float* W[3]  = {(const float*)d_in[3], (const float*)d_in[7],  (const float*)d_in[11]};
    const float* al[3] = {(const float*)d_in[4], (const float*)d_in[8],  (const float*)d_in[12]};
    const float* ar[3] = {(const float*)d_in[5], (const float*)d_in[9],  (const float*)d_in[13]};
    const float* bb[3] = {(const float*)d_in[6], (const float*)d_in[10], (const float*)d_in[14]};
    const float* fcW = (const float*)d_in[15];
    const float* fcb = (const float*)d_in[16];
    float* out = (float*)d_out;

    // ---- workspace layout ----
    char* p = (char*)d_ws;
    float* hnext = (float*)p;               p += (size_t)N_NODES * F_HID * 4;   // 51.2 MB
    float* el    = (float*)p;               p += (size_t)N_NODES * N_HEAD * 4;
    float* er    = (float*)p;               p += (size_t)N_NODES * N_HEAD * 4;
    float* invd  = (float*)p;               p += (size_t)N_NODES * N_HEAD * 4;
    float* abuf  = (float*)p;               p += (size_t)N_EDGES * N_HEAD * 4;  // 4 MB
    unsigned short* hbf   = (unsigned short*)p; p += (size_t)N_NODES * F_IN * 2;  // 51.2 MB (max width)
    unsigned short* featb = (unsigned short*)p; p += (size_t)N_NODES * F_HID * 2; // 25.6 MB
    unsigned short* Wt0   = (unsigned short*)p; p += (size_t)N_REL * F_IN * F_HID * 2;
    unsigned short* Wt1   = (unsigned short*)p; p += (size_t)N_REL * F_HID * F_HID * 2;
    unsigned short* Wt2   = (unsigned short*)p; p += (size_t)N_REL * F_HID * F_HID * 2;
    int* cnt     = (int*)p;                 p += (size_t)N_REL * N_NODES * 4;
    int* cursor  = (int*)p;                 p += (size_t)N_REL * N_NODES * 4;
    int* rowp    = (int*)p;                 p += (size_t)N_REL * (N_NODES + 1) * 4;
    int* bsum    = (int*)p;                 p += (size_t)N_REL * NBLK * 4;
    int* csr_src = (int*)p;                 p += (size_t)N_REL * N_EDGES * 4;

    const int eblk = (N_EDGES + 255) / 256;
    const dim3 egrid(eblk, N_REL);

    // ---- prep: casts + weight transposes + CSR (once per call) ----
    cast_k<<<(N_NODES * F_IN / 4 + 255) / 256, 256, 0, stream>>>(x, hbf, N_NODES * F_IN / 4);
    wprep_k<F_IN><<<(N_REL * F_IN * F_HID + 255) / 256, 256, 0, stream>>>(W[0], Wt0);
    wprep_k<F_HID><<<(N_REL * F_HID * F_HID + 255) / 256, 256, 0, stream>>>(W[1], Wt1);
    wprep_k<F_HID><<<(N_REL * F_HID * F_HID + 255) / 256, 256, 0, stream>>>(W[2], Wt2);

    hipMemsetAsync(cnt, 0, 2 * (size_t)N_REL * N_NODES * sizeof(int), stream);
    count_k<<<egrid, 256, 0, stream>>>(dst, cnt);
    scan1_k<<<dim3(NBLK, N_REL), SCAN_B, 0, stream>>>(cnt, rowp, bsum);
    scan2_k<<<N_REL, 512, 0, stream>>>(bsum);
    scan3_k<<<dim3((N_NODES + 256) / 256, N_REL), 256, 0, stream>>>(rowp, bsum);
    fill_k<<<egrid, 256, 0, stream>>>(src, dst, rowp, cursor, csr_src);

    const int gemm_blocks = (N_NODES + 127) / 128;               // 782
    const int nh_blocks   = (N_NODES * N_HEAD + 255) / 256;
    const int g_blocks    = (N_NODES * 16 + 255) / 256;
    const int act_blocks  = (N_NODES * 32 + 255) / 256;
    const int fc_blocks   = (N_NODES + 31) / 32;

    const unsigned short* Wts[3] = {Wt0, Wt1, Wt2};

    for (int layer = 0; layer < 3; ++layer) {
        for (int r = 0; r < N_REL; ++r) {
            const int* row_r = rowp + (size_t)r * (N_NODES + 1);
            const int* csr_r = csr_src + (size_t)r * N_EDGES;
            if (layer == 0)
                gemm_mfma_k<F_IN><<<gemm_blocks, 256, 0, stream>>>(
                    hbf, Wts[0] + (size_t)r * F_IN * F_HID, featb);
            else
                gemm_mfma_k<F_HID><<<gemm_blocks, 256, 0, stream>>>(
                    hbf, Wts[layer] + (size_t)r * F_HID * F_HID, featb);
            eler_k<<<nh_blocks, 256, 0, stream>>>(
                featb, al[layer] + r * N_HEAD * D_HEAD, ar[layer] + r * N_HEAD * D_HEAD, el, er);
            alpha_k<<<nh_blocks, 256, 0, stream>>>(csr_r, row_r, el, er, abuf, invd);
            if (r == 0)
                gather_k<true><<<g_blocks, 256, 0, stream>>>(csr_r, row_r, featb, abuf, invd, hnext);
            else
                gather_k<false><<<g_blocks, 256, 0, stream>>>(csr_r, row_r, featb, abuf, invd, hnext);
        }
        bias_act_k<<<act_blocks, 256, 0, stream>>>(hnext, bb[layer], hbf, layer < 2 ? 1 : 0);
    }
    fc_k<<<fc_blocks, 256, 0, stream>>>(hbf, fcW, fcb, out);
}

// Round 4
// 736.123 us; speedup vs baseline: 9.3637x; 1.3964x over previous
//
#include <hip/hip_runtime.h>
#include <hip/hip_bf16.h>

#define N_NODES 100000
#define N_EDGES 250000
#define N_REL 4
#define N_HEAD 4
#define D_HEAD 32
#define F_IN 256
#define F_HID 128
#define F_OUT 64
#define LRELU_SLOPE 0.2f

#define SCAN_B 256
#define NBLK ((N_NODES + SCAN_B - 1) / SCAN_B)   // 391

typedef __attribute__((ext_vector_type(8))) short s16x8;
typedef __attribute__((ext_vector_type(8))) unsigned short u16x8;
typedef __attribute__((ext_vector_type(4))) unsigned short u16x4;
typedef __attribute__((ext_vector_type(4))) float f32x4;

__device__ __forceinline__ float bf2f(unsigned short u) {
    return __uint_as_float(((unsigned int)u) << 16);
}
__device__ __forceinline__ unsigned short f2bf(float f) {
    unsigned int x = __float_as_uint(f);
    unsigned int r = x + 0x7fffu + ((x >> 16) & 1u);
    return (unsigned short)(r >> 16);
}
__device__ __forceinline__ void gload_lds16(const void* g, void* l) {
    __builtin_amdgcn_global_load_lds(
        (const __attribute__((address_space(1))) unsigned int*)g,
        (__attribute__((address_space(3))) unsigned int*)l, 16, 0, 0);
}

// ---------------- MFMA GEMM, relation-batched via blockIdx.y ----------------
// C[r][N,128] = A[N,FIN] @ Bt[r][128,FIN]^T   (A,Bt bf16 row-major; C bf16)
template<int FIN>
__global__ __launch_bounds__(256) void gemm_mfma_k(const unsigned short* __restrict__ A,
                                                   const unsigned short* __restrict__ BtAll,
                                                   unsigned short* __restrict__ CAll) {
    const int rel = blockIdx.y;
    const unsigned short* Bt = BtAll + (size_t)rel * F_HID * FIN;
    unsigned short* C = CAll + (size_t)rel * N_NODES * F_HID;

    __shared__ short As[128 * 64];   // [row][k] bf16, XOR-swizzled chunks
    __shared__ short Bs[128 * 64];
    const int tid = threadIdx.x;
    const int lane = tid & 63;
    const int wave = tid >> 6;
    const int wr = wave >> 1, wc = wave & 1;
    const int row0 = blockIdx.x * 128;

    f32x4 acc[4][4];
#pragma unroll
    for (int m = 0; m < 4; ++m)
#pragma unroll
        for (int n = 0; n < 4; ++n) acc[m][n] = (f32x4)0.f;

    for (int k0 = 0; k0 < FIN; k0 += 64) {
        if (k0) __syncthreads();
#pragma unroll
        for (int i = 0; i < 4; ++i) {
            int flat = i * 256 + tid;
            int r = flat >> 3, ch = flat & 7;
            int sch = ch ^ (r & 7);
            int grow = row0 + r; if (grow > N_NODES - 1) grow = N_NODES - 1;
            gload_lds16(A + (size_t)grow * FIN + k0 + sch * 8, As + (size_t)flat * 8);
        }
#pragma unroll
        for (int i = 0; i < 4; ++i) {
            int flat = i * 256 + tid;
            int r = flat >> 3, ch = flat & 7;
            int sch = ch ^ (r & 7);
            gload_lds16(Bt + (size_t)r * FIN + k0 + sch * 8, Bs + (size_t)flat * 8);
        }
        __syncthreads();
#pragma unroll
        for (int kk = 0; kk < 2; ++kk) {
            s16x8 a[4], b[4];
            const int kb = kk * 64 + (lane >> 4) * 16;
#pragma unroll
            for (int m = 0; m < 4; ++m) {
                int r = wr * 64 + m * 16 + (lane & 15);
                int off = r * 128 + (kb ^ ((r & 7) << 4));
                a[m] = *(const s16x8*)((const char*)As + off);
            }
#pragma unroll
            for (int n = 0; n < 4; ++n) {
                int r = wc * 64 + n * 16 + (lane & 15);
                int off = r * 128 + (kb ^ ((r & 7) << 4));
                b[n] = *(const s16x8*)((const char*)Bs + off);
            }
#pragma unroll
            for (int m = 0; m < 4; ++m)
#pragma unroll
                for (int n = 0; n < 4; ++n)
                    acc[m][n] = __builtin_amdgcn_mfma_f32_16x16x32_bf16(a[m], b[n], acc[m][n], 0, 0, 0);
        }
    }
#pragma unroll
    for (int m = 0; m < 4; ++m) {
#pragma unroll
        for (int q = 0; q < 4; ++q) {
            int r = row0 + wr * 64 + m * 16 + (lane >> 4) * 4 + q;
            if (r < N_NODES) {
#pragma unroll
                for (int n = 0; n < 4; ++n) {
                    int c = wc * 64 + n * 16 + (lane & 15);
                    C[(size_t)r * F_HID + c] = f2bf(acc[m][n][q]);
                }
            }
        }
    }
}

// ---------------- weight prep: W[R][K][128] f32 -> Wt[R][128][K] bf16 ----------------
template<int K>
__global__ __launch_bounds__(256) void wprep_k(const float* __restrict__ W,
                                               unsigned short* __restrict__ Wt) {
    int i = blockIdx.x * 256 + threadIdx.x;
    if (i >= N_REL * K * 128) return;
    int r = i / (K * 128);
    int rem = i - r * K * 128;
    int k = rem >> 7, n = rem & 127;
    Wt[(size_t)r * 128 * K + (size_t)n * K + k] = f2bf(W[i]);
}

__global__ __launch_bounds__(256) void cast_k(const float* __restrict__ in,
                                              unsigned short* __restrict__ out, int n4) {
    int i = blockIdx.x * 256 + threadIdx.x;
    if (i >= n4) return;
    float4 v = *(const float4*)(in + (size_t)i * 4);
    u16x4 o = {f2bf(v.x), f2bf(v.y), f2bf(v.z), f2bf(v.w)};
    *(u16x4*)(out + (size_t)i * 4) = o;
}

// ---------------- CSR build ----------------
__global__ __launch_bounds__(256) void count_k(const int* __restrict__ dst, int* __restrict__ cnt) {
    int e = blockIdx.x * 256 + threadIdx.x;
    if (e >= N_EDGES) return;
    int r = blockIdx.y;
    atomicAdd(&cnt[r * N_NODES + dst[(size_t)r * N_EDGES + e]], 1);
}

__global__ __launch_bounds__(SCAN_B) void scan1_k(const int* __restrict__ cnt,
                                                  int* __restrict__ row, int* __restrict__ bsum) {
    __shared__ int sdata[SCAN_B];
    int r = blockIdx.y;
    int n = blockIdx.x * SCAN_B + threadIdx.x;
    int v = (n < N_NODES) ? cnt[r * N_NODES + n] : 0;
    sdata[threadIdx.x] = v;
    __syncthreads();
    for (int off = 1; off < SCAN_B; off <<= 1) {
        int t = (threadIdx.x >= off) ? sdata[threadIdx.x - off] : 0;
        __syncthreads();
        sdata[threadIdx.x] += t;
        __syncthreads();
    }
    if (n < N_NODES) row[r * (N_NODES + 1) + n] = sdata[threadIdx.x] - v;
    if (threadIdx.x == SCAN_B - 1) bsum[r * NBLK + blockIdx.x] = sdata[threadIdx.x];
}

__global__ __launch_bounds__(512) void scan2_k(int* __restrict__ bsum) {
    __shared__ int sdata[512];
    int r = blockIdx.x;
    int v = (threadIdx.x < NBLK) ? bsum[r * NBLK + threadIdx.x] : 0;
    sdata[threadIdx.x] = v;
    __syncthreads();
    for (int off = 1; off < 512; off <<= 1) {
        int t = (threadIdx.x >= off) ? sdata[threadIdx.x - off] : 0;
        __syncthreads();
        sdata[threadIdx.x] += t;
        __syncthreads();
    }
    if (threadIdx.x < NBLK) bsum[r * NBLK + threadIdx.x] = sdata[threadIdx.x] - v;
}

__global__ __launch_bounds__(256) void scan3_k(int* __restrict__ row, const int* __restrict__ bsum) {
    int r = blockIdx.y;
    int n = blockIdx.x * 256 + threadIdx.x;
    if (n > N_NODES) return;
    if (n == N_NODES) { row[r * (N_NODES + 1) + N_NODES] = N_EDGES; return; }
    row[r * (N_NODES + 1) + n] += bsum[r * NBLK + n / SCAN_B];
}

__global__ __launch_bounds__(256) void fill_k(const int* __restrict__ src, const int* __restrict__ dst,
                                              const int* __restrict__ row, int* __restrict__ cursor,
                                              int* __restrict__ csr_src) {
    int e = blockIdx.x * 256 + threadIdx.x;
    if (e >= N_EDGES) return;
    int r = blockIdx.y;
    int s = src[(size_t)r * N_EDGES + e];
    int d = dst[(size_t)r * N_EDGES + e];
    int p = row[r * (N_NODES + 1) + d] + atomicAdd(&cursor[r * N_NODES + d], 1);
    csr_src[(size_t)r * N_EDGES + p] = s;
}

// ---------------- edge phases (relation-batched via blockIdx.y) ----------------
__global__ __launch_bounds__(256) void eler_k(const unsigned short* __restrict__ featAll,
                                              const float* __restrict__ al,   // [R][H][32] for this layer
                                              const float* __restrict__ ar,
                                              float* __restrict__ el, float* __restrict__ er) {
    int i = blockIdx.x * 256 + threadIdx.x;      // n*4 + h
    if (i >= N_NODES * N_HEAD) return;
    int rel = blockIdx.y;
    int h = i & 3;
    const u16x8* f8 = (const u16x8*)(featAll + (size_t)rel * N_NODES * F_HID + (size_t)i * D_HEAD);
    const float* alr = al + rel * F_HID;
    const float* arr = ar + rel * F_HID;
    float sl = 0.f, sr = 0.f;
#pragma unroll
    for (int q = 0; q < 4; ++q) {
        u16x8 f = f8[q];
#pragma unroll
        for (int j = 0; j < 8; ++j) {
            float fv = bf2f(f[j]);
            sl += fv * alr[h * 32 + q * 8 + j];
            sr += fv * arr[h * 32 + q * 8 + j];
        }
    }
    el[(size_t)rel * N_NODES * N_HEAD + i] = sl;
    er[(size_t)rel * N_NODES * N_HEAD + i] = sr;
}

__global__ __launch_bounds__(256) void alpha_k(const int* __restrict__ csr_srcAll,
                                               const int* __restrict__ rowAll,
                                               const float* __restrict__ el,
                                               const float* __restrict__ er,
                                               float* __restrict__ abuf,
                                               float* __restrict__ invden) {
    int i = blockIdx.x * 256 + threadIdx.x;      // n*4 + h
    if (i >= N_NODES * N_HEAD) return;
    int rel = blockIdx.y;
    int n = i >> 2, h = i & 3;
    const int* row = rowAll + (size_t)rel * (N_NODES + 1);
    const int* cs = csr_srcAll + (size_t)rel * N_EDGES;
    const float* elr = el + (size_t)rel * N_NODES * N_HEAD;
    float* ab = abuf + (size_t)rel * N_EDGES * N_HEAD;
    int st = row[n], en = row[n + 1];
    float erd = er[(size_t)rel * N_NODES * N_HEAD + i];
    float m = -INFINITY;
    for (int p = st; p < en; ++p) {
        float v = elr[cs[p] * 4 + h] + erd;
        v = v > 0.f ? v : LRELU_SLOPE * v;
        m = fmaxf(m, v);
    }
    float sum = 0.f;
    for (int p = st; p < en; ++p) {
        float v = elr[cs[p] * 4 + h] + erd;
        v = v > 0.f ? v : LRELU_SLOPE * v;
        float ee = __expf(v - m);
        ab[p * 4 + h] = ee;
        sum += ee;
    }
    invden[(size_t)rel * N_NODES * N_HEAD + i] = 1.f / fmaxf(sum, 1e-9f);
}

// fused: gather over ALL relations + bias + act + bf16 cast -> hbf
__global__ __launch_bounds__(256) void gather_fused_k(const int* __restrict__ csr_srcAll,
                                                      const int* __restrict__ rowAll,
                                                      const unsigned short* __restrict__ featAll,
                                                      const float* __restrict__ abuf,
                                                      const float* __restrict__ invden,
                                                      const float* __restrict__ bias,  // [R][128]
                                                      unsigned short* __restrict__ hbf,
                                                      int relu) {
    int j = blockIdx.x * 256 + threadIdx.x;      // n*16 + sub
    if (j >= N_NODES * 16) return;
    int n = j >> 4, sub = j & 15;
    int h = sub >> 2;
    float acc[8];
#pragma unroll
    for (int q = 0; q < 8; ++q) acc[q] = 0.f;

#pragma unroll
    for (int rel = 0; rel < N_REL; ++rel) {
        const int* row = rowAll + (size_t)rel * (N_NODES + 1);
        const int* cs = csr_srcAll + (size_t)rel * N_EDGES;
        const float* ab = abuf + (size_t)rel * N_EDGES * N_HEAD;
        const unsigned short* feat = featAll + (size_t)rel * N_NODES * F_HID;
        int st = row[n], en = row[n + 1];
        float racc[8];
#pragma unroll
        for (int q = 0; q < 8; ++q) racc[q] = 0.f;
        for (int p = st; p < en; ++p) {
            int s = cs[p];
            float w = ab[p * 4 + h];
            u16x8 f = *(const u16x8*)(feat + (size_t)s * F_HID + sub * 8);
#pragma unroll
            for (int q = 0; q < 8; ++q) racc[q] += w * bf2f(f[q]);
        }
        float id = invden[(size_t)rel * N_NODES * N_HEAD + n * 4 + h];
#pragma unroll
        for (int q = 0; q < 8; ++q) acc[q] += racc[q] * id;
    }

    int c0 = sub * 8;
    u16x8 o;
#pragma unroll
    for (int q = 0; q < 8; ++q) {
        int c = c0 + q;
        float bs = bias[c] + bias[128 + c] + bias[256 + c] + bias[384 + c];
        float t = acc[q] + bs;
        if (relu) t = fmaxf(t, 0.f);
        o[q] = f2bf(t);
    }
    *(u16x8*)(hbf + (size_t)n * F_HID + c0) = o;
}

// out[N,64] = H_bf16[N,128] @ W[128,64] + b
__global__ __launch_bounds__(256) void fc_k(const unsigned short* __restrict__ Hm,
                                            const float* __restrict__ Wm,
                                            const float* __restrict__ bv,
                                            float* __restrict__ out) {
    __shared__ float Ws[F_HID][F_OUT];
    __shared__ float Hs[32][F_HID];
    const int tid = threadIdx.x;
    const int n0 = blockIdx.x * 32;
    const int tx = tid & 63, ty = tid >> 6;
#pragma unroll
    for (int l = 0; l < 8; ++l) {
        int flat = tid + l * 256;
        int r = flat >> 4, c4 = flat & 15;
        *(float4*)(&Ws[r][c4 * 4]) = *(const float4*)(Wm + r * F_OUT + c4 * 4);
    }
#pragma unroll
    for (int l = 0; l < 2; ++l) {
        int flat = tid + l * 256;
        int r = flat >> 4, c8 = flat & 15;
        u16x8 v = (u16x8)0;
        if (n0 + r < N_NODES)
            v = *(const u16x8*)(Hm + (size_t)(n0 + r) * F_HID + c8 * 8);
#pragma unroll
        for (int q = 0; q < 8; ++q) Hs[r][c8 * 8 + q] = bf2f(v[q]);
    }
    __syncthreads();
    float acc[8];
#pragma unroll
    for (int i = 0; i < 8; ++i) acc[i] = 0.f;
    for (int k = 0; k < F_HID; ++k) {
        float w = Ws[k][tx];
#pragma unroll
        for (int i = 0; i < 8; ++i) acc[i] += Hs[ty * 8 + i][k] * w;
    }
    float bb = bv[tx];
#pragma unroll
    for (int i = 0; i < 8; ++i) {
        int r = n0 + ty * 8 + i;
        if (r < N_NODES) out[(size_t)r * F_OUT + tx] = acc[i] + bb;
    }
}

extern "C" void kernel_launch(void* const* d_in, const int* in_sizes, int n_in,
                              void* d_out, int out_size, void* d_ws, size_t ws_size,
                              hipStream_t stream) {
    const float* x   = (const float*)d_in[0];
    const int*   src = (const int*)d_in[1];
    const int*   dst = (const int*)d_in[2];
    const float* W[3]  = {(const float*)d_in[3], (const float*)d_in[7],  (const float*)d_in[11]};
    const float* al[3] = {(const float*)d_in[4], (const float*)d_in[8],  (const float*)d_in[12]};
    const float* ar[3] = {(const float*)d_in[5], (const float*)d_in[9],  (const float*)d_in[13]};
    const float* bb[3] = {(const float*)d_in[6], (const float*)d_in[10], (const float*)d_in[14]};
    const float* fcW = (const float*)d_in[15];
    const float* fcb = (const float*)d_in[16];
    float* out = (float*)d_out;

    // ---- workspace layout ----
    char* p = (char*)d_ws;
    unsigned short* hbf   = (unsigned short*)p; p += (size_t)N_NODES * F_IN * 2;           // 51.2 MB
    unsigned short* featb = (unsigned short*)p; p += (size_t)N_REL * N_NODES * F_HID * 2;  // 102.4 MB
    float* el    = (float*)p;               p += (size_t)N_REL * N_NODES * N_HEAD * 4;     // 6.4 MB
    float* er    = (float*)p;               p += (size_t)N_REL * N_NODES * N_HEAD * 4;
    float* invd  = (float*)p;               p += (size_t)N_REL * N_NODES * N_HEAD * 4;
    float* abuf  = (float*)p;               p += (size_t)N_REL * N_EDGES * N_HEAD * 4;     // 16 MB
    unsigned short* Wt0   = (unsigned short*)p; p += (size_t)N_REL * F_IN * F_HID * 2;
    unsigned short* Wt1   = (unsigned short*)p; p += (size_t)N_REL * F_HID * F_HID * 2;
    unsigned short* Wt2   = (unsigned short*)p; p += (size_t)N_REL * F_HID * F_HID * 2;
    int* cnt     = (int*)p;                 p += (size_t)N_REL * N_NODES * 4;
    int* cursor  = (int*)p;                 p += (size_t)N_REL * N_NODES * 4;
    int* rowp    = (int*)p;                 p += (size_t)N_REL * (N_NODES + 1) * 4;
    int* bsum    = (int*)p;                 p += (size_t)N_REL * NBLK * 4;
    int* csr_src = (int*)p;                 p += (size_t)N_REL * N_EDGES * 4;

    const int eblk = (N_EDGES + 255) / 256;
    const dim3 egrid(eblk, N_REL);

    // ---- prep (once per call) ----
    cast_k<<<(N_NODES * F_IN / 4 + 255) / 256, 256, 0, stream>>>(x, hbf, N_NODES * F_IN / 4);
    wprep_k<F_IN><<<(N_REL * F_IN * F_HID + 255) / 256, 256, 0, stream>>>(W[0], Wt0);
    wprep_k<F_HID><<<(N_REL * F_HID * F_HID + 255) / 256, 256, 0, stream>>>(W[1], Wt1);
    wprep_k<F_HID><<<(N_REL * F_HID * F_HID + 255) / 256, 256, 0, stream>>>(W[2], Wt2);

    hipMemsetAsync(cnt, 0, 2 * (size_t)N_REL * N_NODES * sizeof(int), stream);
    count_k<<<egrid, 256, 0, stream>>>(dst, cnt);
    scan1_k<<<dim3(NBLK, N_REL), SCAN_B, 0, stream>>>(cnt, rowp, bsum);
    scan2_k<<<N_REL, 512, 0, stream>>>(bsum);
    scan3_k<<<dim3((N_NODES + 256) / 256, N_REL), 256, 0, stream>>>(rowp, bsum);
    fill_k<<<egrid, 256, 0, stream>>>(src, dst, rowp, cursor, csr_src);

    const dim3 gemm_grid((N_NODES + 127) / 128, N_REL);          // 782 x 4
    const dim3 nh_grid((N_NODES * N_HEAD + 255) / 256, N_REL);   // 1563 x 4
    const int g_blocks  = (N_NODES * 16 + 255) / 256;            // 6250
    const int fc_blocks = (N_NODES + 31) / 32;

    const unsigned short* Wts[3] = {Wt0, Wt1, Wt2};

    for (int layer = 0; layer < 3; ++layer) {
        if (layer == 0)
            gemm_mfma_k<F_IN><<<gemm_grid, 256, 0, stream>>>(hbf, Wts[0], featb);
        else
            gemm_mfma_k<F_HID><<<gemm_grid, 256, 0, stream>>>(hbf, Wts[layer], featb);
        eler_k<<<nh_grid, 256, 0, stream>>>(featb, al[layer], ar[layer], el, er);
        alpha_k<<<nh_grid, 256, 0, stream>>>(csr_src, rowp, el, er, abuf, invd);
        gather_fused_k<<<g_blocks, 256, 0, stream>>>(csr_src, rowp, featb, abuf, invd,
                                                     bb[layer], hbf, layer < 2 ? 1 : 0);
    }
    fc_k<<<fc_blocks, 256, 0, stream>>>(hbf, fcW, fcb, out);
}

// Round 6
// 663.790 us; speedup vs baseline: 10.3840x; 1.1090x over previous
//
#include <hip/hip_runtime.h>
#include <hip/hip_bf16.h>

#define N_NODES 100000
#define N_EDGES 250000
#define N_REL 4
#define N_HEAD 4
#define D_HEAD 32
#define F_IN 256
#define F_HID 128
#define F_OUT 64
#define LRELU_SLOPE 0.2f

#define SCAN_B 256
#define NBLK ((N_NODES + SCAN_B - 1) / SCAN_B)   // 391

typedef __attribute__((ext_vector_type(8))) short s16x8;
typedef __attribute__((ext_vector_type(8))) unsigned short u16x8;
typedef __attribute__((ext_vector_type(4))) unsigned short u16x4;
typedef __attribute__((ext_vector_type(4))) float f32x4;

__device__ __forceinline__ float bf2f(unsigned short u) {
    return __uint_as_float(((unsigned int)u) << 16);
}
__device__ __forceinline__ unsigned short f2bf(float f) {
    unsigned int x = __float_as_uint(f);
    unsigned int r = x + 0x7fffu + ((x >> 16) & 1u);
    return (unsigned short)(r >> 16);
}
__device__ __forceinline__ void gload_lds16(const void* g, void* l) {
    __builtin_amdgcn_global_load_lds(
        (const __attribute__((address_space(1))) unsigned int*)g,
        (__attribute__((address_space(3))) unsigned int*)l, 16, 0, 0);
}

// ---------------- MFMA GEMM, relation-batched; rel = blockIdx.x (fast) for A-tile L2 reuse ----
// C[r][N,128] = A[N,FIN] @ Bt[r][128,FIN]^T   (A,Bt bf16 row-major; C bf16)
template<int FIN>
__global__ __launch_bounds__(256) void gemm_mfma_k(const unsigned short* __restrict__ A,
                                                   const unsigned short* __restrict__ BtAll,
                                                   unsigned short* __restrict__ CAll) {
    const int rel = blockIdx.x;
    const unsigned short* Bt = BtAll + (size_t)rel * F_HID * FIN;
    unsigned short* C = CAll + (size_t)rel * N_NODES * F_HID;

    __shared__ short As[128 * 64];   // [row][k] bf16, XOR-swizzled chunks
    __shared__ short Bs[128 * 64];
    const int tid = threadIdx.x;
    const int lane = tid & 63;
    const int wave = tid >> 6;
    const int wr = wave >> 1, wc = wave & 1;
    const int row0 = blockIdx.y * 128;

    f32x4 acc[4][4];
#pragma unroll
    for (int m = 0; m < 4; ++m)
#pragma unroll
        for (int n = 0; n < 4; ++n) acc[m][n] = (f32x4)0.f;

    for (int k0 = 0; k0 < FIN; k0 += 64) {
        if (k0) __syncthreads();
#pragma unroll
        for (int i = 0; i < 4; ++i) {
            int flat = i * 256 + tid;
            int r = flat >> 3, ch = flat & 7;
            int sch = ch ^ (r & 7);
            int grow = row0 + r; if (grow > N_NODES - 1) grow = N_NODES - 1;
            gload_lds16(A + (size_t)grow * FIN + k0 + sch * 8, As + (size_t)flat * 8);
        }
#pragma unroll
        for (int i = 0; i < 4; ++i) {
            int flat = i * 256 + tid;
            int r = flat >> 3, ch = flat & 7;
            int sch = ch ^ (r & 7);
            gload_lds16(Bt + (size_t)r * FIN + k0 + sch * 8, Bs + (size_t)flat * 8);
        }
        __syncthreads();
#pragma unroll
        for (int kk = 0; kk < 2; ++kk) {
            s16x8 a[4], b[4];
            const int kb = kk * 64 + (lane >> 4) * 16;
#pragma unroll
            for (int m = 0; m < 4; ++m) {
                int r = wr * 64 + m * 16 + (lane & 15);
                int off = r * 128 + (kb ^ ((r & 7) << 4));
                a[m] = *(const s16x8*)((const char*)As + off);
            }
#pragma unroll
            for (int n = 0; n < 4; ++n) {
                int r = wc * 64 + n * 16 + (lane & 15);
                int off = r * 128 + (kb ^ ((r & 7) << 4));
                b[n] = *(const s16x8*)((const char*)Bs + off);
            }
#pragma unroll
            for (int m = 0; m < 4; ++m)
#pragma unroll
                for (int n = 0; n < 4; ++n)
                    acc[m][n] = __builtin_amdgcn_mfma_f32_16x16x32_bf16(a[m], b[n], acc[m][n], 0, 0, 0);
        }
    }
#pragma unroll
    for (int m = 0; m < 4; ++m) {
#pragma unroll
        for (int q = 0; q < 4; ++q) {
            int r = row0 + wr * 64 + m * 16 + (lane >> 4) * 4 + q;
            if (r < N_NODES) {
#pragma unroll
                for (int n = 0; n < 4; ++n) {
                    int c = wc * 64 + n * 16 + (lane & 15);
                    C[(size_t)r * F_HID + c] = f2bf(acc[m][n][q]);
                }
            }
        }
    }
}

// ---------------- weight prep: W[R][K][128] f32 -> Wt[R][128][K] bf16 ----------------
template<int K>
__global__ __launch_bounds__(256) void wprep_k(const float* __restrict__ W,
                                               unsigned short* __restrict__ Wt) {
    int i = blockIdx.x * 256 + threadIdx.x;
    if (i >= N_REL * K * 128) return;
    int r = i / (K * 128);
    int rem = i - r * K * 128;
    int k = rem >> 7, n = rem & 127;
    Wt[(size_t)r * 128 * K + (size_t)n * K + k] = f2bf(W[i]);
}

// WAL[FIN][32]: wal[f][rel*4+h] = sum_d W[rel][f][h*32+d]*al[rel][h][d]; +16 for ar
template<int FIN>
__global__ __launch_bounds__(256) void walprep_k(const float* __restrict__ W,
                                                 const float* __restrict__ al,
                                                 const float* __restrict__ ar,
                                                 float* __restrict__ wal) {
    int i = blockIdx.x * 256 + threadIdx.x;   // rel*FIN*4 + f*4 + h
    if (i >= N_REL * FIN * 4) return;
    int rel = i / (FIN * 4);
    int rem = i - rel * FIN * 4;
    int f = rem >> 2, h = rem & 3;
    const float* wrow = W + ((size_t)rel * FIN + f) * F_HID + h * D_HEAD;
    const float* alv = al + ((size_t)rel * N_HEAD + h) * D_HEAD;
    const float* arv = ar + ((size_t)rel * N_HEAD + h) * D_HEAD;
    float sl = 0.f, sr = 0.f;
#pragma unroll
    for (int d = 0; d < D_HEAD; ++d) {
        float w = wrow[d];
        sl += w * alv[d];
        sr += w * arv[d];
    }
    wal[(size_t)f * 32 + rel * 4 + h] = sl;
    wal[(size_t)f * 32 + 16 + rel * 4 + h] = sr;
}

// el/er for ALL relations from hbf: EL[N,32] = hbf[N,FIN] @ WAL[FIN,32]
// thread: jt = tid&3 owns outputs jt*8..jt*8+7 for 4 rows (rg, rg+64, rg+128, rg+192)
template<int FIN>
__global__ __launch_bounds__(256) void eler_wal_k(const unsigned short* __restrict__ hbf,
                                                  const float* __restrict__ wal,
                                                  float* __restrict__ el,
                                                  float* __restrict__ er) {
    __shared__ float walS[FIN * 32];
    for (int l = threadIdx.x; l < FIN * 8; l += 256)
        ((float4*)walS)[l] = ((const float4*)wal)[l];
    __syncthreads();
    const int jt = threadIdx.x & 3;
    const int rg = threadIdx.x >> 2;
    const int rbase = blockIdx.x * 256;
    float acc[4][8];
#pragma unroll
    for (int i = 0; i < 4; ++i)
#pragma unroll
        for (int o = 0; o < 8; ++o) acc[i][o] = 0.f;

    for (int f0 = 0; f0 < FIN; f0 += 8) {
        u16x8 hv8[4];
#pragma unroll
        for (int i = 0; i < 4; ++i) {
            int row = rbase + rg + 64 * i;
            hv8[i] = (row < N_NODES) ? *(const u16x8*)(hbf + (size_t)row * FIN + f0) : (u16x8)0;
        }
#pragma unroll
        for (int q = 0; q < 8; ++q) {
            float4 w0 = *(const float4*)&walS[(f0 + q) * 32 + jt * 8];
            float4 w1 = *(const float4*)&walS[(f0 + q) * 32 + jt * 8 + 4];
#pragma unroll
            for (int i = 0; i < 4; ++i) {
                float hv = bf2f(hv8[i][q]);
                acc[i][0] += hv * w0.x; acc[i][1] += hv * w0.y;
                acc[i][2] += hv * w0.z; acc[i][3] += hv * w0.w;
                acc[i][4] += hv * w1.x; acc[i][5] += hv * w1.y;
                acc[i][6] += hv * w1.z; acc[i][7] += hv * w1.w;
            }
        }
    }
#pragma unroll
    for (int i = 0; i < 4; ++i) {
        int row = rbase + rg + 64 * i;
        if (row < N_NODES) {
#pragma unroll
            for (int o = 0; o < 8; ++o) {
                int j = jt * 8 + o;
                int rel = (j >> 2) & 3, h = j & 3;
                float v = acc[i][o];
                if (j < 16) el[(size_t)rel * N_NODES * N_HEAD + row * 4 + h] = v;
                else        er[(size_t)rel * N_NODES * N_HEAD + row * 4 + h] = v;
            }
        }
    }
}

__global__ __launch_bounds__(256) void cast_k(const float* __restrict__ in,
                                              unsigned short* __restrict__ out, int n4) {
    int i = blockIdx.x * 256 + threadIdx.x;
    if (i >= n4) return;
    float4 v = *(const float4*)(in + (size_t)i * 4);
    u16x4 o = {f2bf(v.x), f2bf(v.y), f2bf(v.z), f2bf(v.w)};
    *(u16x4*)(out + (size_t)i * 4) = o;
}

// ---------------- CSR build ----------------
__global__ __launch_bounds__(256) void count_k(const int* __restrict__ dst, int* __restrict__ cnt) {
    int e = blockIdx.x * 256 + threadIdx.x;
    if (e >= N_EDGES) return;
    int r = blockIdx.y;
    atomicAdd(&cnt[r * N_NODES + dst[(size_t)r * N_EDGES + e]], 1);
}

__global__ __launch_bounds__(SCAN_B) void scan1_k(const int* __restrict__ cnt,
                                                  int* __restrict__ row, int* __restrict__ bsum) {
    __shared__ int sdata[SCAN_B];
    int r = blockIdx.y;
    int n = blockIdx.x * SCAN_B + threadIdx.x;
    int v = (n < N_NODES) ? cnt[r * N_NODES + n] : 0;
    sdata[threadIdx.x] = v;
    __syncthreads();
    for (int off = 1; off < SCAN_B; off <<= 1) {
        int t = (threadIdx.x >= off) ? sdata[threadIdx.x - off] : 0;
        __syncthreads();
        sdata[threadIdx.x] += t;
        __syncthreads();
    }
    if (n < N_NODES) row[r * (N_NODES + 1) + n] = sdata[threadIdx.x] - v;
    if (threadIdx.x == SCAN_B - 1) bsum[r * NBLK + blockIdx.x] = sdata[threadIdx.x];
}

__global__ __launch_bounds__(512) void scan2_k(int* __restrict__ bsum) {
    __shared__ int sdata[512];
    int r = blockIdx.x;
    int v = (threadIdx.x < NBLK) ? bsum[r * NBLK + threadIdx.x] : 0;
    sdata[threadIdx.x] = v;
    __syncthreads();
    for (int off = 1; off < 512; off <<= 1) {
        int t = (threadIdx.x >= off) ? sdata[threadIdx.x - off] : 0;
        __syncthreads();
        sdata[threadIdx.x] += t;
        __syncthreads();
    }
    if (threadIdx.x < NBLK) bsum[r * NBLK + threadIdx.x] = sdata[threadIdx.x] - v;
}

__global__ __launch_bounds__(256) void scan3_k(int* __restrict__ row, const int* __restrict__ bsum) {
    int r = blockIdx.y;
    int n = blockIdx.x * 256 + threadIdx.x;
    if (n > N_NODES) return;
    if (n == N_NODES) { row[r * (N_NODES + 1) + N_NODES] = N_EDGES; return; }
    row[r * (N_NODES + 1) + n] += bsum[r * NBLK + n / SCAN_B];
}

__global__ __launch_bounds__(256) void fill_k(const int* __restrict__ src, const int* __restrict__ dst,
                                              const int* __restrict__ row, int* __restrict__ cursor,
                                              int* __restrict__ csr_src) {
    int e = blockIdx.x * 256 + threadIdx.x;
    if (e >= N_EDGES) return;
    int r = blockIdx.y;
    int s = src[(size_t)r * N_EDGES + e];
    int d = dst[(size_t)r * N_EDGES + e];
    int p = row[r * (N_NODES + 1) + d] + atomicAdd(&cursor[r * N_NODES + d], 1);
    csr_src[(size_t)r * N_EDGES + p] = s;
}

// ---------------- edge softmax (relation-batched) ----------------
__global__ __launch_bounds__(256) void alpha_k(const int* __restrict__ csr_srcAll,
                                               const int* __restrict__ rowAll,
                                               const float* __restrict__ el,
                                               const float* __restrict__ er,
                                               float* __restrict__ abuf,
                                               float* __restrict__ invden) {
    int i = blockIdx.x * 256 + threadIdx.x;      // n*4 + h
    if (i >= N_NODES * N_HEAD) return;
    int rel = blockIdx.y;
    int n = i >> 2, h = i & 3;
    const int* row = rowAll + (size_t)rel * (N_NODES + 1);
    const int* cs = csr_srcAll + (size_t)rel * N_EDGES;
    const float* elr = el + (size_t)rel * N_NODES * N_HEAD;
    float* ab = abuf + (size_t)rel * N_EDGES * N_HEAD;
    int st = row[n], en = row[n + 1];
    float erd = er[(size_t)rel * N_NODES * N_HEAD + i];
    float m = -INFINITY;
    for (int p = st; p < en; ++p) {
        float v = elr[cs[p] * 4 + h] + erd;
        v = v > 0.f ? v : LRELU_SLOPE * v;
        m = fmaxf(m, v);
    }
    float sum = 0.f;
    for (int p = st; p < en; ++p) {
        float v = elr[cs[p] * 4 + h] + erd;
        v = v > 0.f ? v : LRELU_SLOPE * v;
        float ee = __expf(v - m);
        ab[p * 4 + h] = ee;
        sum += ee;
    }
    invden[(size_t)rel * N_NODES * N_HEAD + i] = 1.f / fmaxf(sum, 1e-9f);
}

// fused: gather over ALL relations + bias + act + bf16 cast -> hbf
__global__ __launch_bounds__(256) void gather_fused_k(const int* __restrict__ csr_srcAll,
                                                      const int* __restrict__ rowAll,
                                                      const unsigned short* __restrict__ featAll,
                                                      const float* __restrict__ abuf,
                                                      const float* __restrict__ invden,
                                                      const float* __restrict__ bias,  // [R][128]
                                                      unsigned short* __restrict__ hbf,
                                                      int relu) {
    int j = blockIdx.x * 256 + threadIdx.x;      // n*16 + sub
    if (j >= N_NODES * 16) return;
    int n = j >> 4, sub = j & 15;
    int h = sub >> 2;
    float acc[8];
#pragma unroll
    for (int q = 0; q < 8; ++q) acc[q] = 0.f;

#pragma unroll
    for (int rel = 0; rel < N_REL; ++rel) {
        const int* row = rowAll + (size_t)rel * (N_NODES + 1);
        const int* cs = csr_srcAll + (size_t)rel * N_EDGES;
        const float* ab = abuf + (size_t)rel * N_EDGES * N_HEAD;
        const unsigned short* feat = featAll + (size_t)rel * N_NODES * F_HID;
        int st = row[n], en = row[n + 1];
        float racc[8];
#pragma unroll
        for (int q = 0; q < 8; ++q) racc[q] = 0.f;
        for (int p = st; p < en; ++p) {
            int s = cs[p];
            float w = ab[p * 4 + h];
            u16x8 f = *(const u16x8*)(feat + (size_t)s * F_HID + sub * 8);
#pragma unroll
            for (int q = 0; q < 8; ++q) racc[q] += w * bf2f(f[q]);
        }
        float id = invden[(size_t)rel * N_NODES * N_HEAD + n * 4 + h];
#pragma unroll
        for (int q = 0; q < 8; ++q) acc[q] += racc[q] * id;
    }

    int c0 = sub * 8;
    u16x8 o;
#pragma unroll
    for (int q = 0; q < 8; ++q) {
        int c = c0 + q;
        float bs = bias[c] + bias[128 + c] + bias[256 + c] + bias[384 + c];
        float t = acc[q] + bs;
        if (relu) t = fmaxf(t, 0.f);
        o[q] = f2bf(t);
    }
    *(u16x8*)(hbf + (size_t)n * F_HID + c0) = o;
}

// out[N,64] = H_bf16[N,128] @ W[128,64] + b
__global__ __launch_bounds__(256) void fc_k(const unsigned short* __restrict__ Hm,
                                            const float* __restrict__ Wm,
                                            const float* __restrict__ bv,
                                            float* __restrict__ out) {
    __shared__ float Ws[F_HID][F_OUT];
    __shared__ float Hs[32][F_HID];
    const int tid = threadIdx.x;
    const int n0 = blockIdx.x * 32;
    const int tx = tid & 63, ty = tid >> 6;
#pragma unroll
    for (int l = 0; l < 8; ++l) {
        int flat = tid + l * 256;
        int r = flat >> 4, c4 = flat & 15;
        *(float4*)(&Ws[r][c4 * 4]) = *(const float4*)(Wm + r * F_OUT + c4 * 4);
    }
#pragma unroll
    for (int l = 0; l < 2; ++l) {
        int flat = tid + l * 256;
        int r = flat >> 4, c8 = flat & 15;
        u16x8 v = (u16x8)0;
        if (n0 + r < N_NODES)
            v = *(const u16x8*)(Hm + (size_t)(n0 + r) * F_HID + c8 * 8);
#pragma unroll
        for (int q = 0; q < 8; ++q) Hs[r][c8 * 8 + q] = bf2f(v[q]);
    }
    __syncthreads();
    float acc[8];
#pragma unroll
    for (int i = 0; i < 8; ++i) acc[i] = 0.f;
    for (int k = 0; k < F_HID; ++k) {
        float w = Ws[k][tx];
#pragma unroll
        for (int i = 0; i < 8; ++i) acc[i] += Hs[ty * 8 + i][k] * w;
    }
    float bb = bv[tx];
#pragma unroll
    for (int i = 0; i < 8; ++i) {
        int r = n0 + ty * 8 + i;
        if (r < N_NODES) out[(size_t)r * F_OUT + tx] = acc[i] + bb;
    }
}

extern "C" void kernel_launch(void* const* d_in, const int* in_sizes, int n_in,
                              void* d_out, int out_size, void* d_ws, size_t ws_size,
                              hipStream_t stream) {
    const float* x   = (const float*)d_in[0];
    const int*   src = (const int*)d_in[1];
    const int*   dst = (const int*)d_in[2];
    const float* W[3]  = {(const float*)d_in[3], (const float*)d_in[7],  (const float*)d_in[11]};
    const float* al[3] = {(const float*)d_in[4], (const float*)d_in[8],  (const float*)d_in[12]};
    const float* ar[3] = {(const float*)d_in[5], (const float*)d_in[9],  (const float*)d_in[13]};
    const float* bb[3] = {(const float*)d_in[6], (const float*)d_in[10], (const float*)d_in[14]};
    const float* fcW = (const float*)d_in[15];
    const float* fcb = (const float*)d_in[16];
    float* out = (float*)d_out;

    // ---- workspace layout ----
    char* p = (char*)d_ws;
    unsigned short* hbf   = (unsigned short*)p; p += (size_t)N_NODES * F_IN * 2;           // 51.2 MB
    unsigned short* featb = (unsigned short*)p; p += (size_t)N_REL * N_NODES * F_HID * 2;  // 102.4 MB
    float* el    = (float*)p;               p += (size_t)N_REL * N_NODES * N_HEAD * 4;     // 6.4 MB
    float* er    = (float*)p;               p += (size_t)N_REL * N_NODES * N_HEAD * 4;
    float* invd  = (float*)p;               p += (size_t)N_REL * N_NODES * N_HEAD * 4;
    float* abuf  = (float*)p;               p += (size_t)N_REL * N_EDGES * N_HEAD * 4;     // 16 MB
    float* wal0  = (float*)p;               p += (size_t)F_IN * 32 * 4;
    float* wal1  = (float*)p;               p += (size_t)F_HID * 32 * 4;
    float* wal2  = (float*)p;               p += (size_t)F_HID * 32 * 4;
    unsigned short* Wt0   = (unsigned short*)p; p += (size_t)N_REL * F_IN * F_HID * 2;
    unsigned short* Wt1   = (unsigned short*)p; p += (size_t)N_REL * F_HID * F_HID * 2;
    unsigned short* Wt2   = (unsigned short*)p; p += (size_t)N_REL * F_HID * F_HID * 2;
    int* cnt     = (int*)p;                 p += (size_t)N_REL * N_NODES * 4;
    int* cursor  = (int*)p;                 p += (size_t)N_REL * N_NODES * 4;
    int* rowp    = (int*)p;                 p += (size_t)N_REL * (N_NODES + 1) * 4;
    int* bsum    = (int*)p;                 p += (size_t)N_REL * NBLK * 4;
    int* csr_src = (int*)p;                 p += (size_t)N_REL * N_EDGES * 4;

    const int eblk = (N_EDGES + 255) / 256;
    const dim3 egrid(eblk, N_REL);

    // ---- prep (once per call) ----
    cast_k<<<(N_NODES * F_IN / 4 + 255) / 256, 256, 0, stream>>>(x, hbf, N_NODES * F_IN / 4);
    wprep_k<F_IN><<<(N_REL * F_IN * F_HID + 255) / 256, 256, 0, stream>>>(W[0], Wt0);
    wprep_k<F_HID><<<(N_REL * F_HID * F_HID + 255) / 256, 256, 0, stream>>>(W[1], Wt1);
    wprep_k<F_HID><<<(N_REL * F_HID * F_HID + 255) / 256, 256, 0, stream>>>(W[2], Wt2);
    walprep_k<F_IN><<<(N_REL * F_IN * 4 + 255) / 256, 256, 0, stream>>>(W[0], al[0], ar[0], wal0);
    walprep_k<F_HID><<<(N_REL * F_HID * 4 + 255) / 256, 256, 0, stream>>>(W[1], al[1], ar[1], wal1);
    walprep_k<F_HID><<<(N_REL * F_HID * 4 + 255) / 256, 256, 0, stream>>>(W[2], al[2], ar[2], wal2);

    hipMemsetAsync(cnt, 0, 2 * (size_t)N_REL * N_NODES * sizeof(int), stream);
    count_k<<<egrid, 256, 0, stream>>>(dst, cnt);
    scan1_k<<<dim3(NBLK, N_REL), SCAN_B, 0, stream>>>(cnt, rowp, bsum);
    scan2_k<<<N_REL, 512, 0, stream>>>(bsum);
    scan3_k<<<dim3((N_NODES + 256) / 256, N_REL), 256, 0, stream>>>(rowp, bsum);
    fill_k<<<egrid, 256, 0, stream>>>(src, dst, rowp, cursor, csr_src);

    const dim3 gemm_grid(N_REL, (N_NODES + 127) / 128);          // rel fast-varying
    const dim3 nh_grid((N_NODES * N_HEAD + 255) / 256, N_REL);
    const int ew_blocks = (N_NODES + 255) / 256;                 // 391
    const int g_blocks  = (N_NODES * 16 + 255) / 256;            // 6250
    const int fc_blocks = (N_NODES + 31) / 32;

    const unsigned short* Wts[3] = {Wt0, Wt1, Wt2};
    const float* wals[3] = {wal0, wal1, wal2};

    for (int layer = 0; layer < 3; ++layer) {
        if (layer == 0) {
            gemm_mfma_k<F_IN><<<gemm_grid, 256, 0, stream>>>(hbf, Wts[0], featb);
            eler_wal_k<F_IN><<<ew_blocks, 256, 0, stream>>>(hbf, wals[0], el, er);
        } else {
            gemm_mfma_k<F_HID><<<gemm_grid, 256, 0, stream>>>(hbf, Wts[layer], featb);
            eler_wal_k<F_HID><<<ew_blocks, 256, 0, stream>>>(hbf, wals[layer], el, er);
        }
        alpha_k<<<nh_grid, 256, 0, stream>>>(csr_src, rowp, el, er, abuf, invd);
        gather_fused_k<<<g_blocks, 256, 0, stream>>>(csr_src, rowp, featb, abuf, invd,
                                                     bb[layer], hbf, layer < 2 ? 1 : 0);
    }
    fc_k<<<fc_blocks, 256, 0, stream>>>(hbf, fcW, fcb, out);
}

// Round 7
// 600.023 us; speedup vs baseline: 11.4876x; 1.1063x over previous
//
#include <hip/hip_runtime.h>
#include <hip/hip_bf16.h>

#define N_NODES 100000
#define N_EDGES 250000
#define N_REL 4
#define N_HEAD 4
#define D_HEAD 32
#define F_IN 256
#define F_HID 128
#define F_OUT 64
#define LRELU_SLOPE 0.2f

#define SCAN_B 256
#define NBLK ((N_NODES + SCAN_B - 1) / SCAN_B)   // 391

typedef __attribute__((ext_vector_type(8))) short s16x8;
typedef __attribute__((ext_vector_type(8))) unsigned short u16x8;
typedef __attribute__((ext_vector_type(4))) unsigned short u16x4;
typedef __attribute__((ext_vector_type(4))) float f32x4;

__device__ __forceinline__ float bf2f(unsigned short u) {
    return __uint_as_float(((unsigned int)u) << 16);
}
__device__ __forceinline__ unsigned short f2bf(float f) {
    unsigned int x = __float_as_uint(f);
    unsigned int r = x + 0x7fffu + ((x >> 16) & 1u);
    return (unsigned short)(r >> 16);
}
__device__ __forceinline__ void gload_lds16(const void* g, void* l) {
    __builtin_amdgcn_global_load_lds(
        (const __attribute__((address_space(1))) unsigned int*)g,
        (__attribute__((address_space(3))) unsigned int*)l, 16, 0, 0);
}

// ---------------- MFMA GEMM, relation-batched; rel = blockIdx.x (fast) for A-tile L2 reuse ----
// C[r][N,128] = A[N,FIN] @ Bt[r][128,FIN]^T   (A,Bt bf16 row-major; C bf16)
template<int FIN>
__global__ __launch_bounds__(256) void gemm_mfma_k(const unsigned short* __restrict__ A,
                                                   const unsigned short* __restrict__ BtAll,
                                                   unsigned short* __restrict__ CAll) {
    const int rel = blockIdx.x;
    const unsigned short* Bt = BtAll + (size_t)rel * F_HID * FIN;
    unsigned short* C = CAll + (size_t)rel * N_NODES * F_HID;

    __shared__ short As[128 * 64];   // [row][k] bf16, XOR-swizzled chunks
    __shared__ short Bs[128 * 64];
    const int tid = threadIdx.x;
    const int lane = tid & 63;
    const int wave = tid >> 6;
    const int wr = wave >> 1, wc = wave & 1;
    const int row0 = blockIdx.y * 128;

    f32x4 acc[4][4];
#pragma unroll
    for (int m = 0; m < 4; ++m)
#pragma unroll
        for (int n = 0; n < 4; ++n) acc[m][n] = (f32x4)0.f;

    for (int k0 = 0; k0 < FIN; k0 += 64) {
        if (k0) __syncthreads();
#pragma unroll
        for (int i = 0; i < 4; ++i) {
            int flat = i * 256 + tid;
            int r = flat >> 3, ch = flat & 7;
            int sch = ch ^ (r & 7);
            int grow = row0 + r; if (grow > N_NODES - 1) grow = N_NODES - 1;
            gload_lds16(A + (size_t)grow * FIN + k0 + sch * 8, As + (size_t)flat * 8);
        }
#pragma unroll
        for (int i = 0; i < 4; ++i) {
            int flat = i * 256 + tid;
            int r = flat >> 3, ch = flat & 7;
            int sch = ch ^ (r & 7);
            gload_lds16(Bt + (size_t)r * FIN + k0 + sch * 8, Bs + (size_t)flat * 8);
        }
        __syncthreads();
#pragma unroll
        for (int kk = 0; kk < 2; ++kk) {
            s16x8 a[4], b[4];
            const int kb = kk * 64 + (lane >> 4) * 16;
#pragma unroll
            for (int m = 0; m < 4; ++m) {
                int r = wr * 64 + m * 16 + (lane & 15);
                int off = r * 128 + (kb ^ ((r & 7) << 4));
                a[m] = *(const s16x8*)((const char*)As + off);
            }
#pragma unroll
            for (int n = 0; n < 4; ++n) {
                int r = wc * 64 + n * 16 + (lane & 15);
                int off = r * 128 + (kb ^ ((r & 7) << 4));
                b[n] = *(const s16x8*)((const char*)Bs + off);
            }
#pragma unroll
            for (int m = 0; m < 4; ++m)
#pragma unroll
                for (int n = 0; n < 4; ++n)
                    acc[m][n] = __builtin_amdgcn_mfma_f32_16x16x32_bf16(a[m], b[n], acc[m][n], 0, 0, 0);
        }
    }
#pragma unroll
    for (int m = 0; m < 4; ++m) {
#pragma unroll
        for (int q = 0; q < 4; ++q) {
            int r = row0 + wr * 64 + m * 16 + (lane >> 4) * 4 + q;
            if (r < N_NODES) {
#pragma unroll
                for (int n = 0; n < 4; ++n) {
                    int c = wc * 64 + n * 16 + (lane & 15);
                    C[(size_t)r * F_HID + c] = f2bf(acc[m][n][q]);
                }
            }
        }
    }
}

// ---------------- weight prep: W[R][K][128] f32 -> Wt[R][128][K] bf16 ----------------
template<int K>
__global__ __launch_bounds__(256) void wprep_k(const float* __restrict__ W,
                                               unsigned short* __restrict__ Wt) {
    int i = blockIdx.x * 256 + threadIdx.x;
    if (i >= N_REL * K * 128) return;
    int r = i / (K * 128);
    int rem = i - r * K * 128;
    int k = rem >> 7, n = rem & 127;
    Wt[(size_t)r * 128 * K + (size_t)n * K + k] = f2bf(W[i]);
}

// WAL[FIN][32]: wal[f][rel*4+h] = sum_d W[rel][f][h*32+d]*al[rel][h][d]; +16 for ar
template<int FIN>
__global__ __launch_bounds__(256) void walprep_k(const float* __restrict__ W,
                                                 const float* __restrict__ al,
                                                 const float* __restrict__ ar,
                                                 float* __restrict__ wal) {
    int i = blockIdx.x * 256 + threadIdx.x;   // rel*FIN*4 + f*4 + h
    if (i >= N_REL * FIN * 4) return;
    int rel = i / (FIN * 4);
    int rem = i - rel * FIN * 4;
    int f = rem >> 2, h = rem & 3;
    const float* wrow = W + ((size_t)rel * FIN + f) * F_HID + h * D_HEAD;
    const float* alv = al + ((size_t)rel * N_HEAD + h) * D_HEAD;
    const float* arv = ar + ((size_t)rel * N_HEAD + h) * D_HEAD;
    float sl = 0.f, sr = 0.f;
#pragma unroll
    for (int d = 0; d < D_HEAD; ++d) {
        float w = wrow[d];
        sl += w * alv[d];
        sr += w * arv[d];
    }
    wal[(size_t)f * 32 + rel * 4 + h] = sl;
    wal[(size_t)f * 32 + 16 + rel * 4 + h] = sr;
}

// el/er for ALL relations from hbf: EL[N,32] = hbf[N,FIN] @ WAL[FIN,32]
template<int FIN>
__global__ __launch_bounds__(256) void eler_wal_k(const unsigned short* __restrict__ hbf,
                                                  const float* __restrict__ wal,
                                                  float* __restrict__ el,
                                                  float* __restrict__ er) {
    __shared__ float walS[FIN * 32];
    for (int l = threadIdx.x; l < FIN * 8; l += 256)
        ((float4*)walS)[l] = ((const float4*)wal)[l];
    __syncthreads();
    const int jt = threadIdx.x & 3;
    const int rg = threadIdx.x >> 2;
    const int rbase = blockIdx.x * 256;
    float acc[4][8];
#pragma unroll
    for (int i = 0; i < 4; ++i)
#pragma unroll
        for (int o = 0; o < 8; ++o) acc[i][o] = 0.f;

    for (int f0 = 0; f0 < FIN; f0 += 8) {
        u16x8 hv8[4];
#pragma unroll
        for (int i = 0; i < 4; ++i) {
            int row = rbase + rg + 64 * i;
            hv8[i] = (row < N_NODES) ? *(const u16x8*)(hbf + (size_t)row * FIN + f0) : (u16x8)0;
        }
#pragma unroll
        for (int q = 0; q < 8; ++q) {
            float4 w0 = *(const float4*)&walS[(f0 + q) * 32 + jt * 8];
            float4 w1 = *(const float4*)&walS[(f0 + q) * 32 + jt * 8 + 4];
#pragma unroll
            for (int i = 0; i < 4; ++i) {
                float hv = bf2f(hv8[i][q]);
                acc[i][0] += hv * w0.x; acc[i][1] += hv * w0.y;
                acc[i][2] += hv * w0.z; acc[i][3] += hv * w0.w;
                acc[i][4] += hv * w1.x; acc[i][5] += hv * w1.y;
                acc[i][6] += hv * w1.z; acc[i][7] += hv * w1.w;
            }
        }
    }
#pragma unroll
    for (int i = 0; i < 4; ++i) {
        int row = rbase + rg + 64 * i;
        if (row < N_NODES) {
#pragma unroll
            for (int o = 0; o < 8; ++o) {
                int j = jt * 8 + o;
                int rel = (j >> 2) & 3, h = j & 3;
                float v = acc[i][o];
                if (j < 16) el[(size_t)rel * N_NODES * N_HEAD + row * 4 + h] = v;
                else        er[(size_t)rel * N_NODES * N_HEAD + row * 4 + h] = v;
            }
        }
    }
}

__global__ __launch_bounds__(256) void cast_k(const float* __restrict__ in,
                                              unsigned short* __restrict__ out, int n4) {
    int i = blockIdx.x * 256 + threadIdx.x;
    if (i >= n4) return;
    float4 v = *(const float4*)(in + (size_t)i * 4);
    u16x4 o = {f2bf(v.x), f2bf(v.y), f2bf(v.z), f2bf(v.w)};
    *(u16x4*)(out + (size_t)i * 4) = o;
}

// ---------------- CSR build ----------------
__global__ __launch_bounds__(256) void count_k(const int* __restrict__ dst, int* __restrict__ cnt) {
    int e = blockIdx.x * 256 + threadIdx.x;
    if (e >= N_EDGES) return;
    int r = blockIdx.y;
    atomicAdd(&cnt[r * N_NODES + dst[(size_t)r * N_EDGES + e]], 1);
}

__global__ __launch_bounds__(SCAN_B) void scan1_k(const int* __restrict__ cnt,
                                                  int* __restrict__ row, int* __restrict__ bsum) {
    __shared__ int sdata[SCAN_B];
    int r = blockIdx.y;
    int n = blockIdx.x * SCAN_B + threadIdx.x;
    int v = (n < N_NODES) ? cnt[r * N_NODES + n] : 0;
    sdata[threadIdx.x] = v;
    __syncthreads();
    for (int off = 1; off < SCAN_B; off <<= 1) {
        int t = (threadIdx.x >= off) ? sdata[threadIdx.x - off] : 0;
        __syncthreads();
        sdata[threadIdx.x] += t;
        __syncthreads();
    }
    if (n < N_NODES) row[r * (N_NODES + 1) + n] = sdata[threadIdx.x] - v;
    if (threadIdx.x == SCAN_B - 1) bsum[r * NBLK + blockIdx.x] = sdata[threadIdx.x];
}

__global__ __launch_bounds__(512) void scan2_k(int* __restrict__ bsum) {
    __shared__ int sdata[512];
    int r = blockIdx.x;
    int v = (threadIdx.x < NBLK) ? bsum[r * NBLK + threadIdx.x] : 0;
    sdata[threadIdx.x] = v;
    __syncthreads();
    for (int off = 1; off < 512; off <<= 1) {
        int t = (threadIdx.x >= off) ? sdata[threadIdx.x - off] : 0;
        __syncthreads();
        sdata[threadIdx.x] += t;
        __syncthreads();
    }
    if (threadIdx.x < NBLK) bsum[r * NBLK + threadIdx.x] = sdata[threadIdx.x] - v;
}

__global__ __launch_bounds__(256) void scan3_k(int* __restrict__ row, const int* __restrict__ bsum) {
    int r = blockIdx.y;
    int n = blockIdx.x * 256 + threadIdx.x;
    if (n > N_NODES) return;
    if (n == N_NODES) { row[r * (N_NODES + 1) + N_NODES] = N_EDGES; return; }
    row[r * (N_NODES + 1) + n] += bsum[r * NBLK + n / SCAN_B];
}

__global__ __launch_bounds__(256) void fill_k(const int* __restrict__ src, const int* __restrict__ dst,
                                              const int* __restrict__ row, int* __restrict__ cursor,
                                              int* __restrict__ csr_src) {
    int e = blockIdx.x * 256 + threadIdx.x;
    if (e >= N_EDGES) return;
    int r = blockIdx.y;
    int s = src[(size_t)r * N_EDGES + e];
    int d = dst[(size_t)r * N_EDGES + e];
    int p = row[r * (N_NODES + 1) + d] + atomicAdd(&cursor[r * N_NODES + d], 1);
    csr_src[(size_t)r * N_EDGES + p] = s;
}

// ---------------- fused: single-pass edge softmax + gather + bias + act ----------------
// softmax shift-invariance: alpha = exp(v)/sum(exp(v)); v = lrelu(el+er) is O(10) -> f32 safe
__global__ __launch_bounds__(256) void gather_fused_k(const int* __restrict__ csr_srcAll,
                                                      const int* __restrict__ rowAll,
                                                      const unsigned short* __restrict__ featAll,
                                                      const float* __restrict__ el,
                                                      const float* __restrict__ er,
                                                      const float* __restrict__ bias,  // [R][128]
                                                      unsigned short* __restrict__ hbf,
                                                      int relu) {
    int j = blockIdx.x * 256 + threadIdx.x;      // n*16 + sub
    if (j >= N_NODES * 16) return;
    int n = j >> 4, sub = j & 15;
    int h = sub >> 2;
    float acc[8];
#pragma unroll
    for (int q = 0; q < 8; ++q) acc[q] = 0.f;

#pragma unroll
    for (int rel = 0; rel < N_REL; ++rel) {
        const int* row = rowAll + (size_t)rel * (N_NODES + 1);
        const int* cs = csr_srcAll + (size_t)rel * N_EDGES;
        const float* elr = el + (size_t)rel * N_NODES * N_HEAD;
        const unsigned short* feat = featAll + (size_t)rel * N_NODES * F_HID;
        int st = row[n], en = row[n + 1];
        if (st == en) continue;
        float erd = er[(size_t)rel * N_NODES * N_HEAD + n * 4 + h];
        float sum = 0.f;
        float racc[8];
#pragma unroll
        for (int q = 0; q < 8; ++q) racc[q] = 0.f;
        for (int p = st; p < en; ++p) {
            int s = cs[p];
            float v = elr[s * 4 + h] + erd;
            v = v > 0.f ? v : LRELU_SLOPE * v;
            float ee = __expf(v);
            sum += ee;
            u16x8 f = *(const u16x8*)(feat + (size_t)s * F_HID + sub * 8);
#pragma unroll
            for (int q = 0; q < 8; ++q) racc[q] += ee * bf2f(f[q]);
        }
        float id = 1.f / fmaxf(sum, 1e-30f);
#pragma unroll
        for (int q = 0; q < 8; ++q) acc[q] += racc[q] * id;
    }

    int c0 = sub * 8;
    u16x8 o;
#pragma unroll
    for (int q = 0; q < 8; ++q) {
        int c = c0 + q;
        float bs = bias[c] + bias[128 + c] + bias[256 + c] + bias[384 + c];
        float t = acc[q] + bs;
        if (relu) t = fmaxf(t, 0.f);
        o[q] = f2bf(t);
    }
    *(u16x8*)(hbf + (size_t)n * F_HID + c0) = o;
}

// out[N,64] = H_bf16[N,128] @ W[128,64] + b
__global__ __launch_bounds__(256) void fc_k(const unsigned short* __restrict__ Hm,
                                            const float* __restrict__ Wm,
                                            const float* __restrict__ bv,
                                            float* __restrict__ out) {
    __shared__ float Ws[F_HID][F_OUT];
    __shared__ float Hs[32][F_HID];
    const int tid = threadIdx.x;
    const int n0 = blockIdx.x * 32;
    const int tx = tid & 63, ty = tid >> 6;
#pragma unroll
    for (int l = 0; l < 8; ++l) {
        int flat = tid + l * 256;
        int r = flat >> 4, c4 = flat & 15;
        *(float4*)(&Ws[r][c4 * 4]) = *(const float4*)(Wm + r * F_OUT + c4 * 4);
    }
#pragma unroll
    for (int l = 0; l < 2; ++l) {
        int flat = tid + l * 256;
        int r = flat >> 4, c8 = flat & 15;
        u16x8 v = (u16x8)0;
        if (n0 + r < N_NODES)
            v = *(const u16x8*)(Hm + (size_t)(n0 + r) * F_HID + c8 * 8);
#pragma unroll
        for (int q = 0; q < 8; ++q) Hs[r][c8 * 8 + q] = bf2f(v[q]);
    }
    __syncthreads();
    float acc[8];
#pragma unroll
    for (int i = 0; i < 8; ++i) acc[i] = 0.f;
    for (int k = 0; k < F_HID; ++k) {
        float w = Ws[k][tx];
#pragma unroll
        for (int i = 0; i < 8; ++i) acc[i] += Hs[ty * 8 + i][k] * w;
    }
    float bb = bv[tx];
#pragma unroll
    for (int i = 0; i < 8; ++i) {
        int r = n0 + ty * 8 + i;
        if (r < N_NODES) out[(size_t)r * F_OUT + tx] = acc[i] + bb;
    }
}

extern "C" void kernel_launch(void* const* d_in, const int* in_sizes, int n_in,
                              void* d_out, int out_size, void* d_ws, size_t ws_size,
                              hipStream_t stream) {
    const float* x   = (const float*)d_in[0];
    const int*   src = (const int*)d_in[1];
    const int*   dst = (const int*)d_in[2];
    const float* W[3]  = {(const float*)d_in[3], (const float*)d_in[7],  (const float*)d_in[11]};
    const float* al[3] = {(const float*)d_in[4], (const float*)d_in[8],  (const float*)d_in[12]};
    const float* ar[3] = {(const float*)d_in[5], (const float*)d_in[9],  (const float*)d_in[13]};
    const float* bb[3] = {(const float*)d_in[6], (const float*)d_in[10], (const float*)d_in[14]};
    const float* fcW = (const float*)d_in[15];
    const float* fcb = (const float*)d_in[16];
    float* out = (float*)d_out;

    // ---- workspace layout ----
    char* p = (char*)d_ws;
    unsigned short* hbf   = (unsigned short*)p; p += (size_t)N_NODES * F_IN * 2;           // 51.2 MB
    unsigned short* featb = (unsigned short*)p; p += (size_t)N_REL * N_NODES * F_HID * 2;  // 102.4 MB
    float* el    = (float*)p;               p += (size_t)N_REL * N_NODES * N_HEAD * 4;     // 6.4 MB
    float* er    = (float*)p;               p += (size_t)N_REL * N_NODES * N_HEAD * 4;
    float* wal0  = (float*)p;               p += (size_t)F_IN * 32 * 4;
    float* wal1  = (float*)p;               p += (size_t)F_HID * 32 * 4;
    float* wal2  = (float*)p;               p += (size_t)F_HID * 32 * 4;
    unsigned short* Wt0   = (unsigned short*)p; p += (size_t)N_REL * F_IN * F_HID * 2;
    unsigned short* Wt1   = (unsigned short*)p; p += (size_t)N_REL * F_HID * F_HID * 2;
    unsigned short* Wt2   = (unsigned short*)p; p += (size_t)N_REL * F_HID * F_HID * 2;
    int* cnt     = (int*)p;                 p += (size_t)N_REL * N_NODES * 4;
    int* cursor  = (int*)p;                 p += (size_t)N_REL * N_NODES * 4;
    int* rowp    = (int*)p;                 p += (size_t)N_REL * (N_NODES + 1) * 4;
    int* bsum    = (int*)p;                 p += (size_t)N_REL * NBLK * 4;
    int* csr_src = (int*)p;                 p += (size_t)N_REL * N_EDGES * 4;

    const int eblk = (N_EDGES + 255) / 256;
    const dim3 egrid(eblk, N_REL);

    // ---- prep (once per call) ----
    cast_k<<<(N_NODES * F_IN / 4 + 255) / 256, 256, 0, stream>>>(x, hbf, N_NODES * F_IN / 4);
    wprep_k<F_IN><<<(N_REL * F_IN * F_HID + 255) / 256, 256, 0, stream>>>(W[0], Wt0);
    wprep_k<F_HID><<<(N_REL * F_HID * F_HID + 255) / 256, 256, 0, stream>>>(W[1], Wt1);
    wprep_k<F_HID><<<(N_REL * F_HID * F_HID + 255) / 256, 256, 0, stream>>>(W[2], Wt2);
    walprep_k<F_IN><<<(N_REL * F_IN * 4 + 255) / 256, 256, 0, stream>>>(W[0], al[0], ar[0], wal0);
    walprep_k<F_HID><<<(N_REL * F_HID * 4 + 255) / 256, 256, 0, stream>>>(W[1], al[1], ar[1], wal1);
    walprep_k<F_HID><<<(N_REL * F_HID * 4 + 255) / 256, 256, 0, stream>>>(W[2], al[2], ar[2], wal2);

    hipMemsetAsync(cnt, 0, 2 * (size_t)N_REL * N_NODES * sizeof(int), stream);
    count_k<<<egrid, 256, 0, stream>>>(dst, cnt);
    scan1_k<<<dim3(NBLK, N_REL), SCAN_B, 0, stream>>>(cnt, rowp, bsum);
    scan2_k<<<N_REL, 512, 0, stream>>>(bsum);
    scan3_k<<<dim3((N_NODES + 256) / 256, N_REL), 256, 0, stream>>>(rowp, bsum);
    fill_k<<<egrid, 256, 0, stream>>>(src, dst, rowp, cursor, csr_src);

    const dim3 gemm_grid(N_REL, (N_NODES + 127) / 128);          // rel fast-varying
    const int ew_blocks = (N_NODES + 255) / 256;                 // 391
    const int g_blocks  = (N_NODES * 16 + 255) / 256;            // 6250
    const int fc_blocks = (N_NODES + 31) / 32;

    const unsigned short* Wts[3] = {Wt0, Wt1, Wt2};
    const float* wals[3] = {wal0, wal1, wal2};

    for (int layer = 0; layer < 3; ++layer) {
        if (layer == 0) {
            gemm_mfma_k<F_IN><<<gemm_grid, 256, 0, stream>>>(hbf, Wts[0], featb);
            eler_wal_k<F_IN><<<ew_blocks, 256, 0, stream>>>(hbf, wals[0], el, er);
        } else {
            gemm_mfma_k<F_HID><<<gemm_grid, 256, 0, stream>>>(hbf, Wts[layer], featb);
            eler_wal_k<F_HID><<<ew_blocks, 256, 0, stream>>>(hbf, wals[layer], el, er);
        }
        gather_fused_k<<<g_blocks, 256, 0, stream>>>(csr_src, rowp, featb, el, er,
                                                     bb[layer], hbf, layer < 2 ? 1 : 0);
    }
    fc_k<<<fc_blocks, 256, 0, stream>>>(hbf, fcW, fcb, out);
}